// Round 1
// baseline (480.671 us; speedup 1.0000x reference)
//
#include <hip/hip_runtime.h>
#include <stdint.h>

#define B_ 4
#define NX_ 1024
#define NY_ 1024
#define C_ 768
#define H_ 12

using bf16x8 = __attribute__((ext_vector_type(8))) short;
using f32x4  = __attribute__((ext_vector_type(4))) float;

__device__ __forceinline__ unsigned short f2bf(float f) {
  union { float f; uint32_t u; } v; v.f = f;
  return (unsigned short)((v.u + 0x7FFFu + ((v.u >> 16) & 1u)) >> 16);  // RNE
}
__device__ __forceinline__ float bf2f(uint32_t h) {
  union { uint32_t u; float f; } v; v.u = h << 16;
  return v.f;
}
__device__ __forceinline__ uint32_t umaxu(uint32_t a, uint32_t b) { return a > b ? a : b; }
__device__ __forceinline__ uint32_t uminu(uint32_t a, uint32_t b) { return a < b ? a : b; }
__device__ __forceinline__ float wred_add(float v) {
  #pragma unroll
  for (int m = 32; m >= 1; m >>= 1) v += __shfl_xor(v, m);
  return v;
}

// ---------------- cast f32 -> bf16 (x4 vectorized), optional scale ----------------
__global__ void cast_v4_kernel(const float4* __restrict__ src, uint2* __restrict__ dst,
                               int n4, float scale) {
  int i = blockIdx.x * blockDim.x + threadIdx.x;
  int st = gridDim.x * blockDim.x;
  for (; i < n4; i += st) {
    float4 v = src[i];
    uint2 p;
    p.x = (uint32_t)f2bf(v.x * scale) | ((uint32_t)f2bf(v.y * scale) << 16);
    p.y = (uint32_t)f2bf(v.z * scale) | ((uint32_t)f2bf(v.w * scale) << 16);
    dst[i] = p;
  }
}

// ---------------- fused 3x depthwise conv (k=3,5,7 same-pad) + LayerNorm ----------------
// y [B,NY,C] f32 -> ynorm [B,NY,C] bf16. One block per (b,n); 256 thr x 3 channels.
__global__ __launch_bounds__(256) void conv_ln_kernel(
    const float* __restrict__ y,
    const float* __restrict__ w1, const float* __restrict__ b1,
    const float* __restrict__ w2, const float* __restrict__ b2,
    const float* __restrict__ w3, const float* __restrict__ b3,
    const float* __restrict__ lnw, const float* __restrict__ lnb,
    unsigned short* __restrict__ ynorm) {
  __shared__ float red[8];
  const int bn = blockIdx.x;
  const int b = bn >> 10, n = bn & 1023;
  const int t = threadIdx.x;
  const float* yb = y + (size_t)b * NY_ * C_;
  float v[3];
  #pragma unroll
  for (int ci = 0; ci < 3; ci++) {
    const int c = t + (ci << 8);
    float co[7];  // merged cross-correlation taps, dn = -3..3
    #pragma unroll
    for (int k = 0; k < 7; k++) co[k] = w3[c * 7 + k];
    #pragma unroll
    for (int k = 0; k < 5; k++) co[k + 1] += w2[c * 5 + k];
    #pragma unroll
    for (int k = 0; k < 3; k++) co[k + 2] += w1[c * 3 + k];
    float acc = b1[c] + b2[c] + b3[c];
    #pragma unroll
    for (int dn = -3; dn <= 3; dn++) {
      int nn = n + dn;
      float yv = (nn >= 0 && nn < NY_) ? yb[(size_t)nn * C_ + c] : 0.0f;
      acc = fmaf(co[dn + 3], yv, acc);
    }
    v[ci] = acc;
  }
  float s = v[0] + v[1] + v[2];
  float q = v[0] * v[0] + v[1] * v[1] + v[2] * v[2];
  #pragma unroll
  for (int m = 32; m >= 1; m >>= 1) { s += __shfl_xor(s, m); q += __shfl_xor(q, m); }
  const int wid = t >> 6;
  if ((t & 63) == 0) { red[wid] = s; red[4 + wid] = q; }
  __syncthreads();
  const float ts = red[0] + red[1] + red[2] + red[3];
  const float tq = red[4] + red[5] + red[6] + red[7];
  const float inv = 1.0f / 768.0f;
  const float mu = ts * inv;
  const float var = tq * inv - mu * mu;
  const float rs = rsqrtf(var + 1e-5f);
  unsigned short* op = ynorm + (size_t)bn * C_;
  #pragma unroll
  for (int ci = 0; ci < 3; ci++) {
    const int c = t + (ci << 8);
    op[c] = f2bf((v[ci] - mu) * rs * lnw[c] + lnb[c]);
  }
}

// ---------------- direct-L2 MFMA GEMM: C = A @ BT^T  (A [M,K], BT [N,K], bf16) -------------
// wg = 256 thr = 4 waves (2x2), wave tile 64x32, wg tile 128x64.
// MODE 0: q-proj  -> qbuf  [B,H,NX,64] bf16 (A was pre-scaled by 1/8)
// MODE 1: kv-proj -> c<768: kbuf [B,H,NY,64]; c>=768: vT [B,H,64,NY] (transposed, packed b64)
// MODE 2: out-proj -> f32 d_out = acc + bias[c] + resid[row,c]
template <int MODE>
__global__ __launch_bounds__(256) void gemm_bt_kernel(
    const unsigned short* __restrict__ A,
    const unsigned short* __restrict__ BT,
    void* __restrict__ out, void* __restrict__ out2,
    const float* __restrict__ bias, const float* __restrict__ resid,
    int K) {
  const int l = threadIdx.x & 63, w = threadIdx.x >> 6;
  const int lr = l & 15, lk = l >> 4;
  const int m0 = blockIdx.y * 128 + (w >> 1) * 64;
  const int n0 = blockIdx.x * 64 + (w & 1) * 32;

  f32x4 acc[4][2];
  #pragma unroll
  for (int i = 0; i < 4; i++)
    #pragma unroll
    for (int j = 0; j < 2; j++) acc[i][j] = (f32x4){0.f, 0.f, 0.f, 0.f};

  for (int kt = 0; kt < K; kt += 32) {
    bf16x8 a[4], b[2];
    #pragma unroll
    for (int i = 0; i < 4; i++)
      a[i] = *(const bf16x8*)(A + (size_t)(m0 + i * 16 + lr) * K + kt + lk * 8);
    #pragma unroll
    for (int j = 0; j < 2; j++)
      b[j] = *(const bf16x8*)(BT + (size_t)(n0 + j * 16 + lr) * K + kt + lk * 8);
    #pragma unroll
    for (int i = 0; i < 4; i++)
      #pragma unroll
      for (int j = 0; j < 2; j++)
        acc[i][j] = __builtin_amdgcn_mfma_f32_16x16x32_bf16(a[i], b[j], acc[i][j], 0, 0, 0);
  }

  // C/D layout: col = lane&15, row = (lane>>4)*4 + reg  (4 consecutive rows per lane)
  #pragma unroll
  for (int i = 0; i < 4; i++) {
    const int r0 = m0 + i * 16 + lk * 4;
    #pragma unroll
    for (int j = 0; j < 2; j++) {
      const int c = n0 + j * 16 + lr;
      if constexpr (MODE == 0) {
        unsigned short* qb = (unsigned short*)out;
        const int h = c >> 6, d = c & 63;
        #pragma unroll
        for (int g = 0; g < 4; g++) {
          const int row = r0 + g;
          const int bb = row >> 10, nn = row & 1023;
          qb[((((size_t)bb * H_ + h) << 10) + nn) * 64 + d] = f2bf(acc[i][j][g]);
        }
      } else if constexpr (MODE == 1) {
        if (c < C_) {
          unsigned short* kb = (unsigned short*)out;
          const int h = c >> 6, d = c & 63;
          #pragma unroll
          for (int g = 0; g < 4; g++) {
            const int row = r0 + g;
            const int bb = row >> 10, nn = row & 1023;
            kb[((((size_t)bb * H_ + h) << 10) + nn) * 64 + d] = f2bf(acc[i][j][g]);
          }
        } else {
          unsigned short* vt = (unsigned short*)out2;
          const int c2 = c - C_;
          const int h = c2 >> 6, d = c2 & 63;
          const int bb = r0 >> 10, nn = r0 & 1023;  // 4 consecutive n, same b
          uint2 p;
          p.x = (uint32_t)f2bf(acc[i][j][0]) | ((uint32_t)f2bf(acc[i][j][1]) << 16);
          p.y = (uint32_t)f2bf(acc[i][j][2]) | ((uint32_t)f2bf(acc[i][j][3]) << 16);
          *(uint2*)(vt + (((size_t)bb * H_ + h) * 64 + d) * 1024 + nn) = p;
        }
      } else {
        float* fo = (float*)out;
        #pragma unroll
        for (int g = 0; g < 4; g++) {
          const int row = r0 + g;
          const size_t idx = (size_t)row * C_ + c;
          fo[idx] = acc[i][j][g] + bias[c] + resid[idx];
        }
      }
    }
  }
}

// ---------------- fused attention: QK^T -> dual top-k softmax weights -> PV -------------
// One wg per (bh, 32-q-row tile). W LDS [32 q][1024 k] bf16, XOR-swizzled rows.
__global__ __launch_bounds__(256) void attn_kernel(
    const unsigned short* __restrict__ qbuf,   // [B,H,NX,64] bf16, pre-scaled 1/8
    const unsigned short* __restrict__ kbuf,   // [B,H,NY,64] bf16
    const unsigned short* __restrict__ vtbuf,  // [B,H,64,NY] bf16
    unsigned short* __restrict__ ao,           // [B*NX, 768] bf16
    const int* __restrict__ k1p, const int* __restrict__ k2p) {
  __shared__ unsigned short W[32 * 1024];  // 64 KB
  const int l = threadIdx.x & 63, w = threadIdx.x >> 6;
  const int lr = l & 15, lk = l >> 4;
  const int bh = blockIdx.y, qt = blockIdx.x;
  const int kn1 = *k1p, kn2 = *k2p;  // 637, 575
  const size_t base = (size_t)bh * NY_ * 64;
  const unsigned short* Q = qbuf + base + (size_t)qt * 32 * 64;
  const unsigned short* Kp = kbuf + base;
  const unsigned short* Vt = vtbuf + base;

  // Q fragments (B-operand), held in regs for the whole QK^T phase
  bf16x8 qf[2][2];
  #pragma unroll
  for (int j = 0; j < 2; j++)
    #pragma unroll
    for (int s = 0; s < 2; s++)
      qf[j][s] = *(const bf16x8*)(Q + (j * 16 + lr) * 64 + s * 32 + lk * 8);

  // Phase A: swapped QK^T. Wave w owns k-cols [w*256, w*256+256), chunks of 64.
  #pragma unroll 1
  for (int kc = 0; kc < 4; kc++) {
    const int kbase = w * 256 + kc * 64;
    f32x4 acc[4][2];
    #pragma unroll
    for (int i = 0; i < 4; i++)
      #pragma unroll
      for (int j = 0; j < 2; j++) acc[i][j] = (f32x4){0.f, 0.f, 0.f, 0.f};
    #pragma unroll
    for (int s = 0; s < 2; s++) {
      bf16x8 kf[4];
      #pragma unroll
      for (int i = 0; i < 4; i++)
        kf[i] = *(const bf16x8*)(Kp + (size_t)(kbase + i * 16 + lr) * 64 + s * 32 + lk * 8);
      #pragma unroll
      for (int i = 0; i < 4; i++)
        #pragma unroll
        for (int j = 0; j < 2; j++)
          acc[i][j] = __builtin_amdgcn_mfma_f32_16x16x32_bf16(kf[i], qf[j][s], acc[i][j], 0, 0, 0);
    }
    // acc = S^T tile: lane holds 4 consecutive k for one q -> packed b64, swizzled store
    #pragma unroll
    for (int i = 0; i < 4; i++)
      #pragma unroll
      for (int j = 0; j < 2; j++) {
        const int qq = j * 16 + lr;
        const int kk = kbase + i * 16 + lk * 4;
        uint2 p;
        p.x = (uint32_t)f2bf(acc[i][j][0]) | ((uint32_t)f2bf(acc[i][j][1]) << 16);
        p.y = (uint32_t)f2bf(acc[i][j][2]) | ((uint32_t)f2bf(acc[i][j][3]) << 16);
        const int byte = qq * 2048 + ((kk * 2) ^ ((qq & 7) << 4));
        *(uint2*)((char*)W + byte) = p;
      }
  }
  __syncthreads();

  // Phase B: per-row dual exact k-th-largest selection + weight computation.
  // Swizzle-oblivious: read raw 8B chunks, process, write weights back to same spots.
  #pragma unroll 1
  for (int ri = 0; ri < 8; ri++) {
    const int r = w * 8 + ri;
    char* rowp = (char*)W + r * 2048;
    uint2 ch[4];
    #pragma unroll
    for (int cc = 0; cc < 4; cc++) ch[cc] = *(uint2*)(rowp + 8 * l + 512 * cc);
    float vals[16];
    uint32_t keys[16];
    #pragma unroll
    for (int cc = 0; cc < 4; cc++) {
      const uint32_t u0 = ch[cc].x, u1 = ch[cc].y;
      uint32_t hh[4] = {u0 & 0xFFFFu, u0 >> 16, u1 & 0xFFFFu, u1 >> 16};
      #pragma unroll
      for (int g = 0; g < 4; g++) {
        const uint32_t h = hh[g];
        vals[cc * 4 + g] = bf2f(h);
        keys[cc * 4 + g] = h ^ (0x8000u | (0xFFFFu * (h >> 15)));  // order-preserving key
      }
    }
    uint32_t kmx = 0, kmn = 0xFFFFu;
    #pragma unroll
    for (int i = 0; i < 16; i++) { kmx = umaxu(kmx, keys[i]); kmn = uminu(kmn, keys[i]); }
    #pragma unroll
    for (int m = 32; m >= 1; m >>= 1) {
      kmx = umaxu(kmx, (uint32_t)__shfl_xor((int)kmx, m));
      kmn = uminu(kmn, (uint32_t)__shfl_xor((int)kmn, m));
    }
    // find largest t with count(key >= t) >= kn  (ballot -> scalar popcount, SALU-parallel)
    uint32_t lo = kmn, hi = kmx;
    while (lo < hi) {
      const uint32_t mid = (lo + hi + 1) >> 1;
      int cnt = 0;
      #pragma unroll
      for (int i = 0; i < 16; i++) cnt += __popcll(__ballot(keys[i] >= mid));
      if (cnt >= kn1) lo = mid; else hi = mid - 1;
    }
    const uint32_t t1 = lo;
    lo = t1; hi = kmx;  // t2 >= t1 since kn2 < kn1
    while (lo < hi) {
      const uint32_t mid = (lo + hi + 1) >> 1;
      int cnt = 0;
      #pragma unroll
      for (int i = 0; i < 16; i++) cnt += __popcll(__ballot(keys[i] >= mid));
      if (cnt >= kn2) lo = mid; else hi = mid - 1;
    }
    const uint32_t t2 = lo;
    const unsigned short hmx =
        (kmx & 0x8000u) ? (unsigned short)(kmx ^ 0x8000u) : (unsigned short)(kmx ^ 0xFFFFu);
    const float mx = bf2f(hmx);
    float e[16], s1 = 0.f, s2 = 0.f;
    #pragma unroll
    for (int i = 0; i < 16; i++) {
      const float ev = __expf(vals[i] - mx);
      e[i] = ev;
      if (keys[i] >= t1) s1 += ev;
      if (keys[i] >= t2) s2 += ev;
    }
    s1 = wred_add(s1);
    s2 = wred_add(s2);
    const float c1 = 0.6f / s1, c2 = 0.4f / s2;
    #pragma unroll
    for (int cc = 0; cc < 4; cc++) {
      unsigned short pw[4];
      #pragma unroll
      for (int g = 0; g < 4; g++) {
        const int i = cc * 4 + g;
        const float coef = (keys[i] >= t1 ? c1 : 0.f) + (keys[i] >= t2 ? c2 : 0.f);
        pw[g] = f2bf(e[i] * coef);
      }
      uint2 p;
      p.x = (uint32_t)pw[0] | ((uint32_t)pw[1] << 16);
      p.y = (uint32_t)pw[2] | ((uint32_t)pw[3] << 16);
      *(uint2*)(rowp + 8 * l + 512 * cc) = p;
    }
  }
  __syncthreads();

  // Phase C: PV. Wave w owns output d-block [w*16, w*16+16).
  const int d0 = w * 16;
  f32x4 oacc[2];
  oacc[0] = (f32x4){0.f, 0.f, 0.f, 0.f};
  oacc[1] = (f32x4){0.f, 0.f, 0.f, 0.f};
  for (int kt = 0; kt < NY_; kt += 32) {
    const bf16x8 vf = *(const bf16x8*)(Vt + (size_t)(d0 + lr) * 1024 + kt + lk * 8);
    #pragma unroll
    for (int i = 0; i < 2; i++) {
      const int qq = i * 16 + lr;
      const int byte = qq * 2048 + (((kt + lk * 8) * 2) ^ ((qq & 7) << 4));
      const bf16x8 wf = *(const bf16x8*)((char*)W + byte);
      oacc[i] = __builtin_amdgcn_mfma_f32_16x16x32_bf16(wf, vf, oacc[i], 0, 0, 0);
    }
  }
  const int b = bh / H_, h = bh % H_;
  #pragma unroll
  for (int i = 0; i < 2; i++)
    #pragma unroll
    for (int g = 0; g < 4; g++) {
      const int qrow = qt * 32 + i * 16 + lk * 4 + g;
      ao[(size_t)(b * NX_ + qrow) * C_ + h * 64 + d0 + lr] = f2bf(oacc[i][g]);
    }
}

// ---------------- launch ----------------
extern "C" void kernel_launch(void* const* d_in, const int* in_sizes, int n_in,
                              void* d_out, int out_size, void* d_ws, size_t ws_size,
                              hipStream_t stream) {
  const float* x   = (const float*)d_in[0];
  const float* y   = (const float*)d_in[1];
  const float* w1  = (const float*)d_in[2];
  const float* b1  = (const float*)d_in[3];
  const float* w2  = (const float*)d_in[4];
  const float* b2  = (const float*)d_in[5];
  const float* w3  = (const float*)d_in[6];
  const float* b3  = (const float*)d_in[7];
  const float* lnw = (const float*)d_in[8];
  const float* lnb = (const float*)d_in[9];
  const float* qw  = (const float*)d_in[10];
  const float* kvw = (const float*)d_in[11];
  const float* pw  = (const float*)d_in[12];
  const float* pb  = (const float*)d_in[13];
  const int* k1p   = (const int*)d_in[14];
  const int* k2p   = (const int*)d_in[15];

  char* ws = (char*)d_ws;
  size_t off = 0;
  auto alloc = [&](size_t bytes) {
    char* p = ws + off;
    off += (bytes + 255) & ~(size_t)255;
    return p;
  };
  const size_t NTOK = (size_t)B_ * NX_ * C_;  // 3,145,728
  unsigned short* x_bf   = (unsigned short*)alloc(NTOK * 2);
  unsigned short* ynorm  = (unsigned short*)alloc(NTOK * 2);
  unsigned short* qw_bf  = (unsigned short*)alloc((size_t)C_ * C_ * 2);
  unsigned short* kvw_bf = (unsigned short*)alloc((size_t)2 * C_ * C_ * 2);
  unsigned short* pw_bf  = (unsigned short*)alloc((size_t)C_ * C_ * 2);
  unsigned short* qbuf   = (unsigned short*)alloc(NTOK * 2);
  unsigned short* kbuf   = (unsigned short*)alloc(NTOK * 2);
  unsigned short* vtbuf  = (unsigned short*)alloc(NTOK * 2);
  unsigned short* aobuf  = (unsigned short*)alloc(NTOK * 2);

  // casts (x pre-scaled by D^-0.5 = 1/8 so attn scale is free)
  cast_v4_kernel<<<2048, 256, 0, stream>>>((const float4*)x, (uint2*)x_bf, (int)(NTOK / 4), 0.125f);
  cast_v4_kernel<<<576, 256, 0, stream>>>((const float4*)qw, (uint2*)qw_bf, C_ * C_ / 4, 1.0f);
  cast_v4_kernel<<<1152, 256, 0, stream>>>((const float4*)kvw, (uint2*)kvw_bf, 2 * C_ * C_ / 4, 1.0f);
  cast_v4_kernel<<<576, 256, 0, stream>>>((const float4*)pw, (uint2*)pw_bf, C_ * C_ / 4, 1.0f);

  conv_ln_kernel<<<B_ * NY_, 256, 0, stream>>>(y, w1, b1, w2, b2, w3, b3, lnw, lnb, ynorm);

  gemm_bt_kernel<0><<<dim3(C_ / 64, (B_ * NX_) / 128), 256, 0, stream>>>(
      x_bf, qw_bf, qbuf, nullptr, nullptr, nullptr, C_);
  gemm_bt_kernel<1><<<dim3(2 * C_ / 64, (B_ * NY_) / 128), 256, 0, stream>>>(
      ynorm, kvw_bf, kbuf, vtbuf, nullptr, nullptr, C_);

  attn_kernel<<<dim3(NX_ / 32, B_ * H_), 256, 0, stream>>>(qbuf, kbuf, vtbuf, aobuf, k1p, k2p);

  gemm_bt_kernel<2><<<dim3(C_ / 64, (B_ * NX_) / 128), 256, 0, stream>>>(
      aobuf, pw_bf, d_out, nullptr, pb, x, C_);
}

// Round 2
// 406.325 us; speedup vs baseline: 1.1830x; 1.1830x over previous
//
#include <hip/hip_runtime.h>
#include <stdint.h>

#define B_ 4
#define NX_ 1024
#define NY_ 1024
#define C_ 768
#define H_ 12

using bf16x8 = __attribute__((ext_vector_type(8))) short;
using f32x4  = __attribute__((ext_vector_type(4))) float;

__device__ __forceinline__ unsigned short f2bf(float f) {
  union { float f; uint32_t u; } v; v.f = f;
  return (unsigned short)((v.u + 0x7FFFu + ((v.u >> 16) & 1u)) >> 16);  // RNE
}
__device__ __forceinline__ float bf2f(uint32_t h) {
  union { uint32_t u; float f; } v; v.u = h << 16;
  return v.f;
}
__device__ __forceinline__ uint32_t umaxu(uint32_t a, uint32_t b) { return a > b ? a : b; }
__device__ __forceinline__ uint32_t uminu(uint32_t a, uint32_t b) { return a < b ? a : b; }
__device__ __forceinline__ uint32_t rfl(uint32_t v) {
  return (uint32_t)__builtin_amdgcn_readfirstlane((int)v);
}

// ---------------- fused cast f32 -> bf16 for x (scaled 1/8) + 3 weight mats ----------------
__global__ __launch_bounds__(256) void cast_all_kernel(
    const float4* __restrict__ x, uint2* __restrict__ xo,
    const float4* __restrict__ qw, uint2* __restrict__ qo,
    const float4* __restrict__ kvw, uint2* __restrict__ kvo,
    const float4* __restrict__ pw, uint2* __restrict__ po) {
  const int bid = blockIdx.x;
  const float4* s; uint2* d; int base; float sc = 1.0f;
  if (bid < 3072)      { s = x;   d = xo;  base = bid;        sc = 0.125f; }
  else if (bid < 3648) { s = qw;  d = qo;  base = bid - 3072; }
  else if (bid < 4800) { s = kvw; d = kvo; base = bid - 3648; }
  else                 { s = pw;  d = po;  base = bid - 4800; }
  const int i = base * 256 + threadIdx.x;
  float4 v = s[i];
  uint2 p;
  p.x = (uint32_t)f2bf(v.x * sc) | ((uint32_t)f2bf(v.y * sc) << 16);
  p.y = (uint32_t)f2bf(v.z * sc) | ((uint32_t)f2bf(v.w * sc) << 16);
  d[i] = p;
}

// ---------------- fused 3x depthwise conv (k=3,5,7 same-pad) + LayerNorm ----------------
// Block handles 4 consecutive n positions (10 input rows instead of 28).
__global__ __launch_bounds__(256) void conv_ln_kernel(
    const float* __restrict__ y,
    const float* __restrict__ w1, const float* __restrict__ b1,
    const float* __restrict__ w2, const float* __restrict__ b2,
    const float* __restrict__ w3, const float* __restrict__ b3,
    const float* __restrict__ lnw, const float* __restrict__ lnb,
    unsigned short* __restrict__ ynorm) {
  __shared__ float red[4][8];
  const int bn = blockIdx.x;
  const int b = bn >> 8, n0 = (bn & 255) << 2;
  const int t = threadIdx.x;
  const float* yb = y + (size_t)b * NY_ * C_;
  float v[3][4];
  #pragma unroll
  for (int ci = 0; ci < 3; ci++) {
    const int c = t + (ci << 8);
    float co[7];
    #pragma unroll
    for (int k = 0; k < 7; k++) co[k] = w3[c * 7 + k];
    #pragma unroll
    for (int k = 0; k < 5; k++) co[k + 1] += w2[c * 5 + k];
    #pragma unroll
    for (int k = 0; k < 3; k++) co[k + 2] += w1[c * 3 + k];
    const float bias = b1[c] + b2[c] + b3[c];
    float rv[10];
    #pragma unroll
    for (int rr = 0; rr < 10; rr++) {
      const int nn = n0 - 3 + rr;
      rv[rr] = (nn >= 0 && nn < NY_) ? yb[(size_t)nn * C_ + c] : 0.0f;
    }
    #pragma unroll
    for (int oi = 0; oi < 4; oi++) {
      float acc = bias;
      #pragma unroll
      for (int k = 0; k < 7; k++) acc = fmaf(co[k], rv[oi + k], acc);
      v[ci][oi] = acc;
    }
  }
  float s4[4], q4[4];
  #pragma unroll
  for (int oi = 0; oi < 4; oi++) {
    s4[oi] = v[0][oi] + v[1][oi] + v[2][oi];
    q4[oi] = v[0][oi] * v[0][oi] + v[1][oi] * v[1][oi] + v[2][oi] * v[2][oi];
  }
  #pragma unroll
  for (int m = 32; m >= 1; m >>= 1) {
    #pragma unroll
    for (int oi = 0; oi < 4; oi++) {
      s4[oi] += __shfl_xor(s4[oi], m);
      q4[oi] += __shfl_xor(q4[oi], m);
    }
  }
  const int wid = t >> 6;
  if ((t & 63) == 0) {
    #pragma unroll
    for (int oi = 0; oi < 4; oi++) { red[wid][oi] = s4[oi]; red[wid][4 + oi] = q4[oi]; }
  }
  __syncthreads();
  const float inv = 1.0f / 768.0f;
  #pragma unroll
  for (int oi = 0; oi < 4; oi++) {
    const float ts = red[0][oi] + red[1][oi] + red[2][oi] + red[3][oi];
    const float tq = red[0][4 + oi] + red[1][4 + oi] + red[2][4 + oi] + red[3][4 + oi];
    const float mu = ts * inv;
    const float var = tq * inv - mu * mu;
    const float rs = rsqrtf(var + 1e-5f);
    unsigned short* op = ynorm + (size_t)(b * 1024 + n0 + oi) * C_;
    #pragma unroll
    for (int ci = 0; ci < 3; ci++) {
      const int c = t + (ci << 8);
      op[c] = f2bf((v[ci][oi] - mu) * rs * lnw[c] + lnb[c]);
    }
  }
}

// ---------------- direct-L2 MFMA GEMM: C = A @ BT^T  (A [M,768], BT [N,768], bf16) --------
template <int MODE>
__global__ __launch_bounds__(256) void gemm_bt_kernel(
    const unsigned short* __restrict__ A,
    const unsigned short* __restrict__ BT,
    void* __restrict__ out, void* __restrict__ out2,
    const float* __restrict__ bias, const float* __restrict__ resid) {
  constexpr int K = 768;
  const int l = threadIdx.x & 63, w = threadIdx.x >> 6;
  const int lr = l & 15, lk = l >> 4;
  const int m0 = blockIdx.y * 128 + (w >> 1) * 64;
  const int n0 = blockIdx.x * 64 + (w & 1) * 32;

  f32x4 acc[4][2];
  #pragma unroll
  for (int i = 0; i < 4; i++)
    #pragma unroll
    for (int j = 0; j < 2; j++) acc[i][j] = (f32x4){0.f, 0.f, 0.f, 0.f};

  #pragma unroll 4
  for (int kt = 0; kt < K; kt += 32) {
    bf16x8 a[4], b[2];
    #pragma unroll
    for (int i = 0; i < 4; i++)
      a[i] = *(const bf16x8*)(A + (size_t)(m0 + i * 16 + lr) * K + kt + lk * 8);
    #pragma unroll
    for (int j = 0; j < 2; j++)
      b[j] = *(const bf16x8*)(BT + (size_t)(n0 + j * 16 + lr) * K + kt + lk * 8);
    #pragma unroll
    for (int i = 0; i < 4; i++)
      #pragma unroll
      for (int j = 0; j < 2; j++)
        acc[i][j] = __builtin_amdgcn_mfma_f32_16x16x32_bf16(a[i], b[j], acc[i][j], 0, 0, 0);
  }

  #pragma unroll
  for (int i = 0; i < 4; i++) {
    const int r0 = m0 + i * 16 + lk * 4;
    #pragma unroll
    for (int j = 0; j < 2; j++) {
      const int c = n0 + j * 16 + lr;
      if constexpr (MODE == 0) {
        unsigned short* qb = (unsigned short*)out;
        const int h = c >> 6, d = c & 63;
        #pragma unroll
        for (int g = 0; g < 4; g++) {
          const int row = r0 + g;
          const int bb = row >> 10, nn = row & 1023;
          qb[((((size_t)bb * H_ + h) << 10) + nn) * 64 + d] = f2bf(acc[i][j][g]);
        }
      } else if constexpr (MODE == 1) {
        if (c < C_) {
          unsigned short* kb = (unsigned short*)out;
          const int h = c >> 6, d = c & 63;
          #pragma unroll
          for (int g = 0; g < 4; g++) {
            const int row = r0 + g;
            const int bb = row >> 10, nn = row & 1023;
            kb[((((size_t)bb * H_ + h) << 10) + nn) * 64 + d] = f2bf(acc[i][j][g]);
          }
        } else {
          unsigned short* vt = (unsigned short*)out2;
          const int c2 = c - C_;
          const int h = c2 >> 6, d = c2 & 63;
          const int bb = r0 >> 10, nn = r0 & 1023;
          uint2 p;
          p.x = (uint32_t)f2bf(acc[i][j][0]) | ((uint32_t)f2bf(acc[i][j][1]) << 16);
          p.y = (uint32_t)f2bf(acc[i][j][2]) | ((uint32_t)f2bf(acc[i][j][3]) << 16);
          *(uint2*)(vt + (((size_t)bb * H_ + h) * 64 + d) * 1024 + nn) = p;
        }
      } else {
        float* fo = (float*)out;
        #pragma unroll
        for (int g = 0; g < 4; g++) {
          const int row = r0 + g;
          const size_t idx = (size_t)row * C_ + c;
          fo[idx] = acc[i][j][g] + bias[c] + resid[idx];
        }
      }
    }
  }
}

// ---------------- fused attention: QK^T -> dual top-k softmax weights -> PV -------------
// 512 threads = 8 waves per block; 32 q-rows; W [32][1024] bf16 XOR-swizzled; PV k-split.
__global__ __launch_bounds__(512, 4) void attn_kernel(
    const unsigned short* __restrict__ qbuf,   // [B,H,NX,64] bf16, pre-scaled 1/8
    const unsigned short* __restrict__ kbuf,   // [B,H,NY,64] bf16
    const unsigned short* __restrict__ vtbuf,  // [B,H,64,NY] bf16
    unsigned short* __restrict__ ao,           // [B*NX, 768] bf16
    const int* __restrict__ k1p, const int* __restrict__ k2p) {
  __shared__ unsigned short W[32 * 1024];  // 64 KB
  __shared__ float P[32 * 66];             // 8.25 KB padded partial-sum buffer
  const int l = threadIdx.x & 63, w = threadIdx.x >> 6;
  const int lr = l & 15, lk = l >> 4;
  const int bh = blockIdx.y, qt = blockIdx.x;
  const int kn1 = k1p[0], kn2 = k2p[0];  // 637, 575
  const size_t base = (size_t)bh * NY_ * 64;
  const unsigned short* Q = qbuf + base + (size_t)qt * 32 * 64;
  const unsigned short* Kp = kbuf + base;
  const unsigned short* Vt = vtbuf + base;

  // ---- Phase A: swapped QK^T. Wave w owns k-range [w*128, w*128+128). ----
  bf16x8 qf[2][2];
  #pragma unroll
  for (int j = 0; j < 2; j++)
    #pragma unroll
    for (int s = 0; s < 2; s++)
      qf[j][s] = *(const bf16x8*)(Q + (j * 16 + lr) * 64 + s * 32 + lk * 8);

  #pragma unroll
  for (int kc = 0; kc < 2; kc++) {
    const int kbase = w * 128 + kc * 64;
    f32x4 acc[4][2];
    #pragma unroll
    for (int i = 0; i < 4; i++)
      #pragma unroll
      for (int j = 0; j < 2; j++) acc[i][j] = (f32x4){0.f, 0.f, 0.f, 0.f};
    #pragma unroll
    for (int s = 0; s < 2; s++) {
      bf16x8 kf[4];
      #pragma unroll
      for (int i = 0; i < 4; i++)
        kf[i] = *(const bf16x8*)(Kp + (size_t)(kbase + i * 16 + lr) * 64 + s * 32 + lk * 8);
      #pragma unroll
      for (int i = 0; i < 4; i++)
        #pragma unroll
        for (int j = 0; j < 2; j++)
          acc[i][j] = __builtin_amdgcn_mfma_f32_16x16x32_bf16(kf[i], qf[j][s], acc[i][j], 0, 0, 0);
    }
    #pragma unroll
    for (int i = 0; i < 4; i++)
      #pragma unroll
      for (int j = 0; j < 2; j++) {
        const int qq = j * 16 + lr;
        const int kk = kbase + i * 16 + lk * 4;
        uint2 p;
        p.x = (uint32_t)f2bf(acc[i][j][0]) | ((uint32_t)f2bf(acc[i][j][1]) << 16);
        p.y = (uint32_t)f2bf(acc[i][j][2]) | ((uint32_t)f2bf(acc[i][j][3]) << 16);
        const int byte = qq * 2048 + ((kk * 2) ^ ((qq & 7) << 4));
        *(uint2*)((char*)W + byte) = p;
      }
  }
  __syncthreads();

  // ---- Phase B: dual exact k-th-largest + weights. Wave w owns rows w*4..w*4+3. ----
  // Rows processed in pairs; 4 interleaved fixed-16-iter binary searches (SALU bookkeeping).
  #pragma unroll 1
  for (int pr = 0; pr < 2; pr++) {
    const int ra = w * 4 + pr * 2;
    char* rpa = (char*)W + ra * 2048;
    char* rpb = rpa + 2048;
    uint4 a0 = *(uint4*)(rpa + 16 * l);
    uint4 a1 = *(uint4*)(rpa + 16 * l + 1024);
    uint4 b0 = *(uint4*)(rpb + 16 * l);
    uint4 b1 = *(uint4*)(rpb + 16 * l + 1024);
    uint32_t ka[16], kb[16];
    {
      uint32_t ua[8] = {a0.x, a0.y, a0.z, a0.w, a1.x, a1.y, a1.z, a1.w};
      uint32_t ub[8] = {b0.x, b0.y, b0.z, b0.w, b1.x, b1.y, b1.z, b1.w};
      #pragma unroll
      for (int i = 0; i < 8; i++) {
        uint32_t h0 = ua[i] & 0xFFFFu, h1 = ua[i] >> 16;
        ka[2 * i]     = h0 ^ (0x8000u | (0xFFFFu * (h0 >> 15)));
        ka[2 * i + 1] = h1 ^ (0x8000u | (0xFFFFu * (h1 >> 15)));
        h0 = ub[i] & 0xFFFFu; h1 = ub[i] >> 16;
        kb[2 * i]     = h0 ^ (0x8000u | (0xFFFFu * (h0 >> 15)));
        kb[2 * i + 1] = h1 ^ (0x8000u | (0xFFFFu * (h1 >> 15)));
      }
    }
    uint32_t kmxa = 0, kmna = 0xFFFFu, kmxb = 0, kmnb = 0xFFFFu;
    #pragma unroll
    for (int i = 0; i < 16; i++) {
      kmxa = umaxu(kmxa, ka[i]); kmna = uminu(kmna, ka[i]);
      kmxb = umaxu(kmxb, kb[i]); kmnb = uminu(kmnb, kb[i]);
    }
    #pragma unroll
    for (int m = 32; m >= 1; m >>= 1) {
      kmxa = umaxu(kmxa, (uint32_t)__shfl_xor((int)kmxa, m));
      kmna = uminu(kmna, (uint32_t)__shfl_xor((int)kmna, m));
      kmxb = umaxu(kmxb, (uint32_t)__shfl_xor((int)kmxb, m));
      kmnb = uminu(kmnb, (uint32_t)__shfl_xor((int)kmnb, m));
    }
    // scalarize: all search bookkeeping on SALU
    kmxa = rfl(kmxa); kmna = rfl(kmna); kmxb = rfl(kmxb); kmnb = rfl(kmnb);
    uint32_t la1 = kmna, ha1 = kmxa, la2 = kmna, ha2 = kmxa;
    uint32_t lb1 = kmnb, hb1 = kmxb, lb2 = kmnb, hb2 = kmxb;
    #pragma unroll
    for (int it = 0; it < 16; it++) {
      const uint32_t ma1 = (la1 + ha1 + 1) >> 1, ma2 = (la2 + ha2 + 1) >> 1;
      const uint32_t mb1 = (lb1 + hb1 + 1) >> 1, mb2 = (lb2 + hb2 + 1) >> 1;
      int ca1 = 0, ca2 = 0, cb1 = 0, cb2 = 0;
      #pragma unroll
      for (int i = 0; i < 16; i++) {
        ca1 += __popcll(__ballot(ka[i] >= ma1));
        ca2 += __popcll(__ballot(ka[i] >= ma2));
        cb1 += __popcll(__ballot(kb[i] >= mb1));
        cb2 += __popcll(__ballot(kb[i] >= mb2));
      }
      if (ca1 >= kn1) la1 = ma1; else ha1 = ma1 - 1;
      if (ca2 >= kn2) la2 = ma2; else ha2 = ma2 - 1;
      if (cb1 >= kn1) lb1 = mb1; else hb1 = mb1 - 1;
      if (cb2 >= kn2) lb2 = mb2; else hb2 = mb2 - 1;
    }
    const uint32_t t1a = la1, t2a = la2, t1b = lb1, t2b = lb2;
    const float fmxa = bf2f(kmxa ^ ((kmxa & 0x8000u) ? 0x8000u : 0xFFFFu));
    const float fmxb = bf2f(kmxb ^ ((kmxb & 0x8000u) ? 0x8000u : 0xFFFFu));
    float ea[16], eb[16];
    float s1a = 0.f, s2a = 0.f, s1b = 0.f, s2b = 0.f;
    #pragma unroll
    for (int i = 0; i < 16; i++) {
      const uint32_t hda = ka[i] ^ ((ka[i] & 0x8000u) ? 0x8000u : 0xFFFFu);
      const uint32_t hdb = kb[i] ^ ((kb[i] & 0x8000u) ? 0x8000u : 0xFFFFu);
      const float eva = __expf(bf2f(hda) - fmxa);
      const float evb = __expf(bf2f(hdb) - fmxb);
      ea[i] = eva; eb[i] = evb;
      if (ka[i] >= t1a) s1a += eva;
      if (ka[i] >= t2a) s2a += eva;
      if (kb[i] >= t1b) s1b += evb;
      if (kb[i] >= t2b) s2b += evb;
    }
    #pragma unroll
    for (int m = 32; m >= 1; m >>= 1) {
      s1a += __shfl_xor(s1a, m); s2a += __shfl_xor(s2a, m);
      s1b += __shfl_xor(s1b, m); s2b += __shfl_xor(s2b, m);
    }
    const float c1a = 0.6f / s1a, c2a = 0.4f / s2a;
    const float c1b = 0.6f / s1b, c2b = 0.4f / s2b;
    uint32_t oa[8], ob[8];
    #pragma unroll
    for (int i = 0; i < 8; i++) {
      const int i0 = 2 * i, i1 = 2 * i + 1;
      const float wa0 = ea[i0] * ((ka[i0] >= t1a ? c1a : 0.f) + (ka[i0] >= t2a ? c2a : 0.f));
      const float wa1 = ea[i1] * ((ka[i1] >= t1a ? c1a : 0.f) + (ka[i1] >= t2a ? c2a : 0.f));
      const float wb0 = eb[i0] * ((kb[i0] >= t1b ? c1b : 0.f) + (kb[i0] >= t2b ? c2b : 0.f));
      const float wb1 = eb[i1] * ((kb[i1] >= t1b ? c1b : 0.f) + (kb[i1] >= t2b ? c2b : 0.f));
      oa[i] = (uint32_t)f2bf(wa0) | ((uint32_t)f2bf(wa1) << 16);
      ob[i] = (uint32_t)f2bf(wb0) | ((uint32_t)f2bf(wb1) << 16);
    }
    *(uint4*)(rpa + 16 * l)        = (uint4){oa[0], oa[1], oa[2], oa[3]};
    *(uint4*)(rpa + 16 * l + 1024) = (uint4){oa[4], oa[5], oa[6], oa[7]};
    *(uint4*)(rpb + 16 * l)        = (uint4){ob[0], ob[1], ob[2], ob[3]};
    *(uint4*)(rpb + 16 * l + 1024) = (uint4){ob[4], ob[5], ob[6], ob[7]};
  }
  __syncthreads();

  // ---- Phase C: PV, k-split across wave halves. d-block = (w&3)*16, k-half = w>>2. ----
  const int d0 = (w & 3) * 16;
  const int k0 = (w >> 2) * 512;
  f32x4 oacc[2];
  oacc[0] = (f32x4){0.f, 0.f, 0.f, 0.f};
  oacc[1] = (f32x4){0.f, 0.f, 0.f, 0.f};
  #pragma unroll 4
  for (int kt2 = 0; kt2 < 512; kt2 += 32) {
    const int kt = k0 + kt2;
    const bf16x8 vf = *(const bf16x8*)(Vt + (size_t)(d0 + lr) * 1024 + kt + lk * 8);
    #pragma unroll
    for (int i = 0; i < 2; i++) {
      const int qq = i * 16 + lr;
      const int byte = qq * 2048 + (((kt + lk * 8) * 2) ^ ((qq & 7) << 4));
      const bf16x8 wf = *(const bf16x8*)((char*)W + byte);
      oacc[i] = __builtin_amdgcn_mfma_f32_16x16x32_bf16(wf, vf, oacc[i], 0, 0, 0);
    }
  }
  if (w >= 4) {
    #pragma unroll
    for (int i = 0; i < 2; i++)
      #pragma unroll
      for (int g = 0; g < 4; g++)
        P[(i * 16 + lk * 4 + g) * 66 + d0 + lr] = oacc[i][g];
  }
  __syncthreads();
  if (w < 4) {
    const int b = bh / H_, h = bh % H_;
    #pragma unroll
    for (int i = 0; i < 2; i++)
      #pragma unroll
      for (int g = 0; g < 4; g++) {
        const float v = oacc[i][g] + P[(i * 16 + lk * 4 + g) * 66 + d0 + lr];
        const int qrow = qt * 32 + i * 16 + lk * 4 + g;
        ao[(size_t)(b * NX_ + qrow) * C_ + h * 64 + d0 + lr] = f2bf(v);
      }
  }
}

// ---------------- launch ----------------
extern "C" void kernel_launch(void* const* d_in, const int* in_sizes, int n_in,
                              void* d_out, int out_size, void* d_ws, size_t ws_size,
                              hipStream_t stream) {
  const float* x   = (const float*)d_in[0];
  const float* y   = (const float*)d_in[1];
  const float* w1  = (const float*)d_in[2];
  const float* b1  = (const float*)d_in[3];
  const float* w2  = (const float*)d_in[4];
  const float* b2  = (const float*)d_in[5];
  const float* w3  = (const float*)d_in[6];
  const float* b3  = (const float*)d_in[7];
  const float* lnw = (const float*)d_in[8];
  const float* lnb = (const float*)d_in[9];
  const float* qw  = (const float*)d_in[10];
  const float* kvw = (const float*)d_in[11];
  const float* pw  = (const float*)d_in[12];
  const float* pb  = (const float*)d_in[13];
  const int* k1p   = (const int*)d_in[14];
  const int* k2p   = (const int*)d_in[15];

  char* ws = (char*)d_ws;
  size_t off = 0;
  auto alloc = [&](size_t bytes) {
    char* p = ws + off;
    off += (bytes + 255) & ~(size_t)255;
    return p;
  };
  const size_t NTOK = (size_t)B_ * NX_ * C_;
  unsigned short* x_bf   = (unsigned short*)alloc(NTOK * 2);
  unsigned short* ynorm  = (unsigned short*)alloc(NTOK * 2);
  unsigned short* qw_bf  = (unsigned short*)alloc((size_t)C_ * C_ * 2);
  unsigned short* kvw_bf = (unsigned short*)alloc((size_t)2 * C_ * C_ * 2);
  unsigned short* pw_bf  = (unsigned short*)alloc((size_t)C_ * C_ * 2);
  unsigned short* qbuf   = (unsigned short*)alloc(NTOK * 2);
  unsigned short* kbuf   = (unsigned short*)alloc(NTOK * 2);
  unsigned short* vtbuf  = (unsigned short*)alloc(NTOK * 2);
  unsigned short* aobuf  = (unsigned short*)alloc(NTOK * 2);

  cast_all_kernel<<<5376, 256, 0, stream>>>(
      (const float4*)x, (uint2*)x_bf, (const float4*)qw, (uint2*)qw_bf,
      (const float4*)kvw, (uint2*)kvw_bf, (const float4*)pw, (uint2*)pw_bf);

  conv_ln_kernel<<<1024, 256, 0, stream>>>(y, w1, b1, w2, b2, w3, b3, lnw, lnb, ynorm);

  gemm_bt_kernel<0><<<dim3(C_ / 64, (B_ * NX_) / 128), 256, 0, stream>>>(
      x_bf, qw_bf, qbuf, nullptr, nullptr, nullptr);
  gemm_bt_kernel<1><<<dim3(2 * C_ / 64, (B_ * NY_) / 128), 256, 0, stream>>>(
      ynorm, kvw_bf, kbuf, vtbuf, nullptr, nullptr);

  attn_kernel<<<dim3(NX_ / 32, B_ * H_), 512, 0, stream>>>(qbuf, kbuf, vtbuf, aobuf, k1p, k2p);

  gemm_bt_kernel<2><<<dim3(C_ / 64, (B_ * NX_) / 128), 256, 0, stream>>>(
      aobuf, pw_bf, d_out, nullptr, pb, x);
}

// Round 3
// 399.378 us; speedup vs baseline: 1.2035x; 1.0174x over previous
//
#include <hip/hip_runtime.h>
#include <stdint.h>

#define B_ 4
#define NX_ 1024
#define NY_ 1024
#define C_ 768
#define H_ 12

using bf16x8 = __attribute__((ext_vector_type(8))) short;
using f32x4  = __attribute__((ext_vector_type(4))) float;

__device__ __forceinline__ unsigned short f2bf(float f) {
  union { float f; uint32_t u; } v; v.f = f;
  return (unsigned short)((v.u + 0x7FFFu + ((v.u >> 16) & 1u)) >> 16);  // RNE
}
__device__ __forceinline__ float bf2f(uint32_t h) {
  union { uint32_t u; float f; } v; v.u = h << 16;
  return v.f;
}
__device__ __forceinline__ uint32_t umaxu(uint32_t a, uint32_t b) { return a > b ? a : b; }
__device__ __forceinline__ uint32_t uminu(uint32_t a, uint32_t b) { return a < b ? a : b; }
__device__ __forceinline__ uint32_t rfl(uint32_t v) {
  return (uint32_t)__builtin_amdgcn_readfirstlane((int)v);
}
// SALU popcount of a wave-uniform 64-bit mask (ballot result). Keeps the whole
// count/compare/update chain on the scalar pipe (co-issues with VALU).
__device__ __forceinline__ int sbcnt(unsigned long long m) {
  int r;
  asm("s_bcnt1_i32_b64 %0, %1" : "=s"(r) : "s"(m));
  return r;
}

// ---------------- fused cast f32 -> bf16 for x (scaled 1/8) + 3 weight mats ----------------
__global__ __launch_bounds__(256) void cast_all_kernel(
    const float4* __restrict__ x, uint2* __restrict__ xo,
    const float4* __restrict__ qw, uint2* __restrict__ qo,
    const float4* __restrict__ kvw, uint2* __restrict__ kvo,
    const float4* __restrict__ pw, uint2* __restrict__ po) {
  const int bid = blockIdx.x;
  const float4* s; uint2* d; int base; float sc = 1.0f;
  if (bid < 3072)      { s = x;   d = xo;  base = bid;        sc = 0.125f; }
  else if (bid < 3648) { s = qw;  d = qo;  base = bid - 3072; }
  else if (bid < 4800) { s = kvw; d = kvo; base = bid - 3648; }
  else                 { s = pw;  d = po;  base = bid - 4800; }
  const int i = base * 256 + threadIdx.x;
  float4 v = s[i];
  uint2 p;
  p.x = (uint32_t)f2bf(v.x * sc) | ((uint32_t)f2bf(v.y * sc) << 16);
  p.y = (uint32_t)f2bf(v.z * sc) | ((uint32_t)f2bf(v.w * sc) << 16);
  d[i] = p;
}

// ---------------- fused 3x depthwise conv (k=3,5,7 same-pad) + LayerNorm ----------------
__global__ __launch_bounds__(256) void conv_ln_kernel(
    const float* __restrict__ y,
    const float* __restrict__ w1, const float* __restrict__ b1,
    const float* __restrict__ w2, const float* __restrict__ b2,
    const float* __restrict__ w3, const float* __restrict__ b3,
    const float* __restrict__ lnw, const float* __restrict__ lnb,
    unsigned short* __restrict__ ynorm) {
  __shared__ float red[4][8];
  const int bn = blockIdx.x;
  const int b = bn >> 8, n0 = (bn & 255) << 2;
  const int t = threadIdx.x;
  const float* yb = y + (size_t)b * NY_ * C_;
  float v[3][4];
  #pragma unroll
  for (int ci = 0; ci < 3; ci++) {
    const int c = t + (ci << 8);
    float co[7];
    #pragma unroll
    for (int k = 0; k < 7; k++) co[k] = w3[c * 7 + k];
    #pragma unroll
    for (int k = 0; k < 5; k++) co[k + 1] += w2[c * 5 + k];
    #pragma unroll
    for (int k = 0; k < 3; k++) co[k + 2] += w1[c * 3 + k];
    const float bias = b1[c] + b2[c] + b3[c];
    float rv[10];
    #pragma unroll
    for (int rr = 0; rr < 10; rr++) {
      const int nn = n0 - 3 + rr;
      rv[rr] = (nn >= 0 && nn < NY_) ? yb[(size_t)nn * C_ + c] : 0.0f;
    }
    #pragma unroll
    for (int oi = 0; oi < 4; oi++) {
      float acc = bias;
      #pragma unroll
      for (int k = 0; k < 7; k++) acc = fmaf(co[k], rv[oi + k], acc);
      v[ci][oi] = acc;
    }
  }
  float s4[4], q4[4];
  #pragma unroll
  for (int oi = 0; oi < 4; oi++) {
    s4[oi] = v[0][oi] + v[1][oi] + v[2][oi];
    q4[oi] = v[0][oi] * v[0][oi] + v[1][oi] * v[1][oi] + v[2][oi] * v[2][oi];
  }
  #pragma unroll
  for (int m = 32; m >= 1; m >>= 1) {
    #pragma unroll
    for (int oi = 0; oi < 4; oi++) {
      s4[oi] += __shfl_xor(s4[oi], m);
      q4[oi] += __shfl_xor(q4[oi], m);
    }
  }
  const int wid = t >> 6;
  if ((t & 63) == 0) {
    #pragma unroll
    for (int oi = 0; oi < 4; oi++) { red[wid][oi] = s4[oi]; red[wid][4 + oi] = q4[oi]; }
  }
  __syncthreads();
  const float inv = 1.0f / 768.0f;
  #pragma unroll
  for (int oi = 0; oi < 4; oi++) {
    const float ts = red[0][oi] + red[1][oi] + red[2][oi] + red[3][oi];
    const float tq = red[0][4 + oi] + red[1][4 + oi] + red[2][4 + oi] + red[3][4 + oi];
    const float mu = ts * inv;
    const float var = tq * inv - mu * mu;
    const float rs = rsqrtf(var + 1e-5f);
    unsigned short* op = ynorm + (size_t)(b * 1024 + n0 + oi) * C_;
    #pragma unroll
    for (int ci = 0; ci < 3; ci++) {
      const int c = t + (ci << 8);
      op[c] = f2bf((v[ci][oi] - mu) * rs * lnw[c] + lnb[c]);
    }
  }
}

// ---------------- direct-L2 MFMA GEMM: C = A @ BT^T  (A [M,768], BT [N,768], bf16) --------
template <int MODE>
__global__ __launch_bounds__(256) void gemm_bt_kernel(
    const unsigned short* __restrict__ A,
    const unsigned short* __restrict__ BT,
    void* __restrict__ out, void* __restrict__ out2,
    const float* __restrict__ bias, const float* __restrict__ resid) {
  constexpr int K = 768;
  const int l = threadIdx.x & 63, w = threadIdx.x >> 6;
  const int lr = l & 15, lk = l >> 4;
  const int m0 = blockIdx.y * 128 + (w >> 1) * 64;
  const int n0 = blockIdx.x * 64 + (w & 1) * 32;

  f32x4 acc[4][2];
  #pragma unroll
  for (int i = 0; i < 4; i++)
    #pragma unroll
    for (int j = 0; j < 2; j++) acc[i][j] = (f32x4){0.f, 0.f, 0.f, 0.f};

  #pragma unroll 4
  for (int kt = 0; kt < K; kt += 32) {
    bf16x8 a[4], b[2];
    #pragma unroll
    for (int i = 0; i < 4; i++)
      a[i] = *(const bf16x8*)(A + (size_t)(m0 + i * 16 + lr) * K + kt + lk * 8);
    #pragma unroll
    for (int j = 0; j < 2; j++)
      b[j] = *(const bf16x8*)(BT + (size_t)(n0 + j * 16 + lr) * K + kt + lk * 8);
    #pragma unroll
    for (int i = 0; i < 4; i++)
      #pragma unroll
      for (int j = 0; j < 2; j++)
        acc[i][j] = __builtin_amdgcn_mfma_f32_16x16x32_bf16(a[i], b[j], acc[i][j], 0, 0, 0);
  }

  #pragma unroll
  for (int i = 0; i < 4; i++) {
    const int r0 = m0 + i * 16 + lk * 4;
    #pragma unroll
    for (int j = 0; j < 2; j++) {
      const int c = n0 + j * 16 + lr;
      if constexpr (MODE == 0) {
        unsigned short* qb = (unsigned short*)out;
        const int h = c >> 6, d = c & 63;
        #pragma unroll
        for (int g = 0; g < 4; g++) {
          const int row = r0 + g;
          const int bb = row >> 10, nn = row & 1023;
          qb[((((size_t)bb * H_ + h) << 10) + nn) * 64 + d] = f2bf(acc[i][j][g]);
        }
      } else if constexpr (MODE == 1) {
        if (c < C_) {
          unsigned short* kb = (unsigned short*)out;
          const int h = c >> 6, d = c & 63;
          #pragma unroll
          for (int g = 0; g < 4; g++) {
            const int row = r0 + g;
            const int bb = row >> 10, nn = row & 1023;
            kb[((((size_t)bb * H_ + h) << 10) + nn) * 64 + d] = f2bf(acc[i][j][g]);
          }
        } else {
          unsigned short* vt = (unsigned short*)out2;
          const int c2 = c - C_;
          const int h = c2 >> 6, d = c2 & 63;
          const int bb = r0 >> 10, nn = r0 & 1023;
          uint2 p;
          p.x = (uint32_t)f2bf(acc[i][j][0]) | ((uint32_t)f2bf(acc[i][j][1]) << 16);
          p.y = (uint32_t)f2bf(acc[i][j][2]) | ((uint32_t)f2bf(acc[i][j][3]) << 16);
          *(uint2*)(vt + (((size_t)bb * H_ + h) * 64 + d) * 1024 + nn) = p;
        }
      } else {
        float* fo = (float*)out;
        #pragma unroll
        for (int g = 0; g < 4; g++) {
          const int row = r0 + g;
          const size_t idx = (size_t)row * C_ + c;
          fo[idx] = acc[i][j][g] + bias[c] + resid[idx];
        }
      }
    }
  }
}

// ---------------- fused attention: QK^T -> dual top-k softmax weights -> PV -------------
// 16 q-rows per block, 512 threads = 8 waves; W [16][1024] bf16 XOR-swizzled (32 KB);
// 4 blocks/CU. Selection bookkeeping fully on SALU (inline-asm s_bcnt1), adaptive
// scalar while-loops, kn2-search restricted to [t1, kmax].
__global__ __launch_bounds__(512, 8) void attn_kernel(
    const unsigned short* __restrict__ qbuf,   // [B,H,NX,64] bf16, pre-scaled 1/8
    const unsigned short* __restrict__ kbuf,   // [B,H,NY,64] bf16
    const unsigned short* __restrict__ vtbuf,  // [B,H,64,NY] bf16
    unsigned short* __restrict__ ao,           // [B*NX, 768] bf16
    const int* __restrict__ k1p, const int* __restrict__ k2p) {
  __shared__ unsigned short W[16 * 1024];  // 32 KB
  __shared__ float P[16 * 66];             // 4.2 KB partial-sum buffer
  const int l = threadIdx.x & 63, w = threadIdx.x >> 6;
  const int lr = l & 15, lk = l >> 4;
  const int bh = blockIdx.y, qt = blockIdx.x;
  const int kn1 = k1p[0], kn2 = k2p[0];  // 637, 575
  const size_t base = (size_t)bh * NY_ * 64;
  const unsigned short* Q = qbuf + base + (size_t)qt * 16 * 64;
  const unsigned short* Kp = kbuf + base;
  const unsigned short* Vt = vtbuf + base;

  // ---- Phase A: swapped QK^T. Wave w owns k-range [w*128, w*128+128). ----
  bf16x8 qf[2];
  #pragma unroll
  for (int s = 0; s < 2; s++)
    qf[s] = *(const bf16x8*)(Q + lr * 64 + s * 32 + lk * 8);

  #pragma unroll
  for (int kc = 0; kc < 2; kc++) {
    const int kbase = w * 128 + kc * 64;
    f32x4 acc[4];
    #pragma unroll
    for (int i = 0; i < 4; i++) acc[i] = (f32x4){0.f, 0.f, 0.f, 0.f};
    #pragma unroll
    for (int s = 0; s < 2; s++) {
      bf16x8 kf[4];
      #pragma unroll
      for (int i = 0; i < 4; i++)
        kf[i] = *(const bf16x8*)(Kp + (size_t)(kbase + i * 16 + lr) * 64 + s * 32 + lk * 8);
      #pragma unroll
      for (int i = 0; i < 4; i++)
        acc[i] = __builtin_amdgcn_mfma_f32_16x16x32_bf16(kf[i], qf[s], acc[i], 0, 0, 0);
    }
    #pragma unroll
    for (int i = 0; i < 4; i++) {
      const int qq = lr;
      const int kk = kbase + i * 16 + lk * 4;
      uint2 p;
      p.x = (uint32_t)f2bf(acc[i][0]) | ((uint32_t)f2bf(acc[i][1]) << 16);
      p.y = (uint32_t)f2bf(acc[i][2]) | ((uint32_t)f2bf(acc[i][3]) << 16);
      const int byte = qq * 2048 + ((kk * 2) ^ ((qq & 7) << 4));
      *(uint2*)((char*)W + byte) = p;
    }
  }
  __syncthreads();

  // ---- Phase B: dual exact k-th-largest + weights. Wave w owns rows 2w, 2w+1. ----
  {
    char* rpa = (char*)W + (2 * w) * 2048;
    char* rpb = rpa + 2048;
    uint4 a0 = *(uint4*)(rpa + 16 * l);
    uint4 a1 = *(uint4*)(rpa + 16 * l + 1024);
    uint4 b0 = *(uint4*)(rpb + 16 * l);
    uint4 b1 = *(uint4*)(rpb + 16 * l + 1024);
    uint32_t ka[16], kb[16];
    {
      uint32_t ua[8] = {a0.x, a0.y, a0.z, a0.w, a1.x, a1.y, a1.z, a1.w};
      uint32_t ub[8] = {b0.x, b0.y, b0.z, b0.w, b1.x, b1.y, b1.z, b1.w};
      #pragma unroll
      for (int i = 0; i < 8; i++) {
        uint32_t h0 = ua[i] & 0xFFFFu, h1 = ua[i] >> 16;
        ka[2 * i]     = h0 ^ (0x8000u | (0xFFFFu * (h0 >> 15)));
        ka[2 * i + 1] = h1 ^ (0x8000u | (0xFFFFu * (h1 >> 15)));
        h0 = ub[i] & 0xFFFFu; h1 = ub[i] >> 16;
        kb[2 * i]     = h0 ^ (0x8000u | (0xFFFFu * (h0 >> 15)));
        kb[2 * i + 1] = h1 ^ (0x8000u | (0xFFFFu * (h1 >> 15)));
      }
    }
    uint32_t kmxa = 0, kmna = 0xFFFFu, kmxb = 0, kmnb = 0xFFFFu;
    #pragma unroll
    for (int i = 0; i < 16; i++) {
      kmxa = umaxu(kmxa, ka[i]); kmna = uminu(kmna, ka[i]);
      kmxb = umaxu(kmxb, kb[i]); kmnb = uminu(kmnb, kb[i]);
    }
    #pragma unroll
    for (int m = 32; m >= 1; m >>= 1) {
      kmxa = umaxu(kmxa, (uint32_t)__shfl_xor((int)kmxa, m));
      kmna = uminu(kmna, (uint32_t)__shfl_xor((int)kmna, m));
      kmxb = umaxu(kmxb, (uint32_t)__shfl_xor((int)kmxb, m));
      kmnb = uminu(kmnb, (uint32_t)__shfl_xor((int)kmnb, m));
    }
    kmxa = rfl(kmxa); kmna = rfl(kmna); kmxb = rfl(kmxb); kmnb = rfl(kmnb);

    // search t1 (count >= kn1) for both rows jointly; all bookkeeping scalar
    uint32_t la = kmna, ha = kmxa, lb = kmnb, hb = kmxb;
    while (la < ha || lb < hb) {
      const uint32_t ma = (la + ha + 1) >> 1, mb = (lb + hb + 1) >> 1;
      int ca = 0, cb = 0;
      #pragma unroll
      for (int i = 0; i < 16; i++) {
        ca += sbcnt(__ballot(ka[i] >= ma));
        cb += sbcnt(__ballot(kb[i] >= mb));
      }
      if (la < ha) { if (ca >= kn1) la = ma; else ha = ma - 1; }
      if (lb < hb) { if (cb >= kn1) lb = mb; else hb = mb - 1; }
    }
    const uint32_t t1a = la, t1b = lb;
    // search t2 (count >= kn2) restricted to [t1, kmax] (t2 >= t1 since kn2 < kn1)
    la = t1a; ha = kmxa; lb = t1b; hb = kmxb;
    while (la < ha || lb < hb) {
      const uint32_t ma = (la + ha + 1) >> 1, mb = (lb + hb + 1) >> 1;
      int ca = 0, cb = 0;
      #pragma unroll
      for (int i = 0; i < 16; i++) {
        ca += sbcnt(__ballot(ka[i] >= ma));
        cb += sbcnt(__ballot(kb[i] >= mb));
      }
      if (la < ha) { if (ca >= kn2) la = ma; else ha = ma - 1; }
      if (lb < hb) { if (cb >= kn2) lb = mb; else hb = mb - 1; }
    }
    const uint32_t t2a = la, t2b = lb;

    const float fmxa = bf2f(kmxa ^ ((kmxa & 0x8000u) ? 0x8000u : 0xFFFFu));
    const float fmxb = bf2f(kmxb ^ ((kmxb & 0x8000u) ? 0x8000u : 0xFFFFu));
    // pass 1: sums (top = sum over keys>=t2, band = sum over t1<=key<t2)
    float topa = 0.f, banda = 0.f, topb = 0.f, bandb = 0.f;
    #pragma unroll
    for (int i = 0; i < 16; i++) {
      const uint32_t hda = ka[i] ^ ((ka[i] & 0x8000u) ? 0x8000u : 0xFFFFu);
      const uint32_t hdb = kb[i] ^ ((kb[i] & 0x8000u) ? 0x8000u : 0xFFFFu);
      const float eva = __expf(bf2f(hda) - fmxa);
      const float evb = __expf(bf2f(hdb) - fmxb);
      if (ka[i] >= t2a) topa += eva;
      else if (ka[i] >= t1a) banda += eva;
      if (kb[i] >= t2b) topb += evb;
      else if (kb[i] >= t1b) bandb += evb;
    }
    #pragma unroll
    for (int m = 32; m >= 1; m >>= 1) {
      topa += __shfl_xor(topa, m); banda += __shfl_xor(banda, m);
      topb += __shfl_xor(topb, m); bandb += __shfl_xor(bandb, m);
    }
    const float c1a = 0.6f / (topa + banda), c2a = 0.4f / topa;
    const float c1b = 0.6f / (topb + bandb), c2b = 0.4f / topb;
    const float c12a = c1a + c2a, c12b = c1b + c2b;
    // pass 2: weights (recompute exp; keeps register pressure under 64)
    uint32_t oa[8], ob[8];
    #pragma unroll
    for (int i = 0; i < 8; i++) {
      const int i0 = 2 * i, i1 = 2 * i + 1;
      const uint32_t ha0 = ka[i0] ^ ((ka[i0] & 0x8000u) ? 0x8000u : 0xFFFFu);
      const uint32_t ha1 = ka[i1] ^ ((ka[i1] & 0x8000u) ? 0x8000u : 0xFFFFu);
      const uint32_t hb0 = kb[i0] ^ ((kb[i0] & 0x8000u) ? 0x8000u : 0xFFFFu);
      const uint32_t hb1 = kb[i1] ^ ((kb[i1] & 0x8000u) ? 0x8000u : 0xFFFFu);
      const float ca0 = (ka[i0] >= t1a) ? ((ka[i0] >= t2a) ? c12a : c1a) : 0.f;
      const float ca1 = (ka[i1] >= t1a) ? ((ka[i1] >= t2a) ? c12a : c1a) : 0.f;
      const float cb0 = (kb[i0] >= t1b) ? ((kb[i0] >= t2b) ? c12b : c1b) : 0.f;
      const float cb1 = (kb[i1] >= t1b) ? ((kb[i1] >= t2b) ? c12b : c1b) : 0.f;
      const float wa0 = __expf(bf2f(ha0) - fmxa) * ca0;
      const float wa1 = __expf(bf2f(ha1) - fmxa) * ca1;
      const float wb0 = __expf(bf2f(hb0) - fmxb) * cb0;
      const float wb1 = __expf(bf2f(hb1) - fmxb) * cb1;
      oa[i] = (uint32_t)f2bf(wa0) | ((uint32_t)f2bf(wa1) << 16);
      ob[i] = (uint32_t)f2bf(wb0) | ((uint32_t)f2bf(wb1) << 16);
    }
    *(uint4*)(rpa + 16 * l)        = (uint4){oa[0], oa[1], oa[2], oa[3]};
    *(uint4*)(rpa + 16 * l + 1024) = (uint4){oa[4], oa[5], oa[6], oa[7]};
    *(uint4*)(rpb + 16 * l)        = (uint4){ob[0], ob[1], ob[2], ob[3]};
    *(uint4*)(rpb + 16 * l + 1024) = (uint4){ob[4], ob[5], ob[6], ob[7]};
  }
  __syncthreads();

  // ---- Phase C: PV, k-split across wave halves. d-block = (w&3)*16, k-half = w>>2. ----
  const int d0 = (w & 3) * 16;
  const int k0 = (w >> 2) * 512;
  f32x4 oacc = (f32x4){0.f, 0.f, 0.f, 0.f};
  #pragma unroll 4
  for (int kt2 = 0; kt2 < 512; kt2 += 32) {
    const int kt = k0 + kt2;
    const bf16x8 vf = *(const bf16x8*)(Vt + (size_t)(d0 + lr) * 1024 + kt + lk * 8);
    const int qq = lr;
    const int byte = qq * 2048 + (((kt + lk * 8) * 2) ^ ((qq & 7) << 4));
    const bf16x8 wf = *(const bf16x8*)((char*)W + byte);
    oacc = __builtin_amdgcn_mfma_f32_16x16x32_bf16(wf, vf, oacc, 0, 0, 0);
  }
  if (w >= 4) {
    #pragma unroll
    for (int g = 0; g < 4; g++)
      P[(lk * 4 + g) * 66 + d0 + lr] = oacc[g];
  }
  __syncthreads();
  if (w < 4) {
    const int b = bh / H_, h = bh % H_;
    #pragma unroll
    for (int g = 0; g < 4; g++) {
      const float v = oacc[g] + P[(lk * 4 + g) * 66 + d0 + lr];
      const int qrow = qt * 16 + lk * 4 + g;
      ao[(size_t)(b * NX_ + qrow) * C_ + h * 64 + d0 + lr] = f2bf(v);
    }
  }
}

// ---------------- launch ----------------
extern "C" void kernel_launch(void* const* d_in, const int* in_sizes, int n_in,
                              void* d_out, int out_size, void* d_ws, size_t ws_size,
                              hipStream_t stream) {
  const float* x   = (const float*)d_in[0];
  const float* y   = (const float*)d_in[1];
  const float* w1  = (const float*)d_in[2];
  const float* b1  = (const float*)d_in[3];
  const float* w2  = (const float*)d_in[4];
  const float* b2  = (const float*)d_in[5];
  const float* w3  = (const float*)d_in[6];
  const float* b3  = (const float*)d_in[7];
  const float* lnw = (const float*)d_in[8];
  const float* lnb = (const float*)d_in[9];
  const float* qw  = (const float*)d_in[10];
  const float* kvw = (const float*)d_in[11];
  const float* pw  = (const float*)d_in[12];
  const float* pb  = (const float*)d_in[13];
  const int* k1p   = (const int*)d_in[14];
  const int* k2p   = (const int*)d_in[15];

  char* ws = (char*)d_ws;
  size_t off = 0;
  auto alloc = [&](size_t bytes) {
    char* p = ws + off;
    off += (bytes + 255) & ~(size_t)255;
    return p;
  };
  const size_t NTOK = (size_t)B_ * NX_ * C_;
  unsigned short* x_bf   = (unsigned short*)alloc(NTOK * 2);
  unsigned short* ynorm  = (unsigned short*)alloc(NTOK * 2);
  unsigned short* qw_bf  = (unsigned short*)alloc((size_t)C_ * C_ * 2);
  unsigned short* kvw_bf = (unsigned short*)alloc((size_t)2 * C_ * C_ * 2);
  unsigned short* pw_bf  = (unsigned short*)alloc((size_t)C_ * C_ * 2);
  unsigned short* qbuf   = (unsigned short*)alloc(NTOK * 2);
  unsigned short* kbuf   = (unsigned short*)alloc(NTOK * 2);
  unsigned short* vtbuf  = (unsigned short*)alloc(NTOK * 2);
  unsigned short* aobuf  = (unsigned short*)alloc(NTOK * 2);

  cast_all_kernel<<<5376, 256, 0, stream>>>(
      (const float4*)x, (uint2*)x_bf, (const float4*)qw, (uint2*)qw_bf,
      (const float4*)kvw, (uint2*)kvw_bf, (const float4*)pw, (uint2*)pw_bf);

  conv_ln_kernel<<<1024, 256, 0, stream>>>(y, w1, b1, w2, b2, w3, b3, lnw, lnb, ynorm);

  gemm_bt_kernel<0><<<dim3(C_ / 64, (B_ * NX_) / 128), 256, 0, stream>>>(
      x_bf, qw_bf, qbuf, nullptr, nullptr, nullptr);
  gemm_bt_kernel<1><<<dim3(2 * C_ / 64, (B_ * NY_) / 128), 256, 0, stream>>>(
      ynorm, kvw_bf, kbuf, vtbuf, nullptr, nullptr);

  attn_kernel<<<dim3(NX_ / 16, B_ * H_), 512, 0, stream>>>(qbuf, kbuf, vtbuf, aobuf, k1p, k2p);

  gemm_bt_kernel<2><<<dim3(C_ / 64, (B_ * NX_) / 128), 256, 0, stream>>>(
      aobuf, pw_bf, d_out, nullptr, pb, x);
}

// Round 6
// 311.613 us; speedup vs baseline: 1.5425x; 1.2816x over previous
//
#include <hip/hip_runtime.h>
#include <stdint.h>

#define B_ 4
#define NX_ 1024
#define NY_ 1024
#define C_ 768
#define H_ 12

using bf16x8 = __attribute__((ext_vector_type(8))) short;
using f32x4  = __attribute__((ext_vector_type(4))) float;

__device__ __forceinline__ unsigned short f2bf(float f) {
  union { float f; uint32_t u; } v; v.f = f;
  return (unsigned short)((v.u + 0x7FFFu + ((v.u >> 16) & 1u)) >> 16);  // RNE
}
__device__ __forceinline__ float bf2f(uint32_t h) {
  union { uint32_t u; float f; } v; v.u = h << 16;
  return v.f;
}
__device__ __forceinline__ uint32_t umaxu(uint32_t a, uint32_t b) { return a > b ? a : b; }
__device__ __forceinline__ uint32_t uminu(uint32_t a, uint32_t b) { return a < b ? a : b; }
__device__ __forceinline__ uint32_t rfl(uint32_t v) {
  return (uint32_t)__builtin_amdgcn_readfirstlane((int)v);
}
// 2^x via native v_exp_f32 (HIP device overload; __exp2f does not exist in HIP).
__device__ __forceinline__ float exp2_fast(float x) { return exp2f(x); }
// One VALU inst: v_cmp into SGPR pair (VOP3). src0=VGPR, src1=SGPR (1 sgpr read ok).
__device__ __forceinline__ unsigned long long vcmp_ge(uint32_t v, uint32_t t) {
  unsigned long long m;
  asm("v_cmp_ge_u32 %0, %1, %2" : "=s"(m) : "v"(v), "s"(t));
  return m;
}
// SALU popcount of wave-uniform 64-bit mask.
__device__ __forceinline__ int sbcnt(unsigned long long m) {
  int r;
  asm("s_bcnt1_i32_b64 %0, %1" : "=s"(r) : "s"(m));
  return r;
}
#define COUNT16(arr, thr, cnt)                                   \
  {                                                              \
    cnt = 0;                                                     \
    _Pragma("unroll") for (int i_ = 0; i_ < 16; i_++)            \
        cnt += sbcnt(vcmp_ge(arr[i_], thr));                     \
  }

// ---------------- fused pre: conv+LN (blocks 0..1023) + casts (blocks 1024..6399) ----------
__global__ __launch_bounds__(256) void pre_kernel(
    const float* __restrict__ y,
    const float* __restrict__ w1, const float* __restrict__ b1,
    const float* __restrict__ w2, const float* __restrict__ b2,
    const float* __restrict__ w3, const float* __restrict__ b3,
    const float* __restrict__ lnw, const float* __restrict__ lnb,
    unsigned short* __restrict__ ynorm,
    const float4* __restrict__ x, uint2* __restrict__ xo,
    const float4* __restrict__ qw, uint2* __restrict__ qo,
    const float4* __restrict__ kvw, uint2* __restrict__ kvo,
    const float4* __restrict__ pw, uint2* __restrict__ po) {
  __shared__ float red[4][8];
  const int bid = blockIdx.x;
  const int t = threadIdx.x;
  if (bid >= 1024) {
    // ---- cast part. x scaled by (1/8)*log2(e): scores land in log2-domain. ----
    const int cid = bid - 1024;
    const float4* s; uint2* d; int base; float sc = 1.0f;
    if (cid < 3072)      { s = x;   d = xo;  base = cid;        sc = 0.125f * 1.44269504f; }
    else if (cid < 3648) { s = qw;  d = qo;  base = cid - 3072; }
    else if (cid < 4800) { s = kvw; d = kvo; base = cid - 3648; }
    else                 { s = pw;  d = po;  base = cid - 4800; }
    const int i = base * 256 + t;
    float4 v = s[i];
    uint2 p;
    p.x = (uint32_t)f2bf(v.x * sc) | ((uint32_t)f2bf(v.y * sc) << 16);
    p.y = (uint32_t)f2bf(v.z * sc) | ((uint32_t)f2bf(v.w * sc) << 16);
    d[i] = p;
    return;
  }
  // ---- conv + LN part: 4 consecutive n per block ----
  const int b = bid >> 8, n0 = (bid & 255) << 2;
  const float* yb = y + (size_t)b * NY_ * C_;
  float v[3][4];
  #pragma unroll
  for (int ci = 0; ci < 3; ci++) {
    const int c = t + (ci << 8);
    float co[7];
    #pragma unroll
    for (int k = 0; k < 7; k++) co[k] = w3[c * 7 + k];
    #pragma unroll
    for (int k = 0; k < 5; k++) co[k + 1] += w2[c * 5 + k];
    #pragma unroll
    for (int k = 0; k < 3; k++) co[k + 2] += w1[c * 3 + k];
    const float bias = b1[c] + b2[c] + b3[c];
    float rv[10];
    #pragma unroll
    for (int rr = 0; rr < 10; rr++) {
      const int nn = n0 - 3 + rr;
      rv[rr] = (nn >= 0 && nn < NY_) ? yb[(size_t)nn * C_ + c] : 0.0f;
    }
    #pragma unroll
    for (int oi = 0; oi < 4; oi++) {
      float acc = bias;
      #pragma unroll
      for (int k = 0; k < 7; k++) acc = fmaf(co[k], rv[oi + k], acc);
      v[ci][oi] = acc;
    }
  }
  float s4[4], q4[4];
  #pragma unroll
  for (int oi = 0; oi < 4; oi++) {
    s4[oi] = v[0][oi] + v[1][oi] + v[2][oi];
    q4[oi] = v[0][oi] * v[0][oi] + v[1][oi] * v[1][oi] + v[2][oi] * v[2][oi];
  }
  #pragma unroll
  for (int m = 32; m >= 1; m >>= 1) {
    #pragma unroll
    for (int oi = 0; oi < 4; oi++) {
      s4[oi] += __shfl_xor(s4[oi], m);
      q4[oi] += __shfl_xor(q4[oi], m);
    }
  }
  const int wid = t >> 6;
  if ((t & 63) == 0) {
    #pragma unroll
    for (int oi = 0; oi < 4; oi++) { red[wid][oi] = s4[oi]; red[wid][4 + oi] = q4[oi]; }
  }
  __syncthreads();
  const float inv = 1.0f / 768.0f;
  #pragma unroll
  for (int oi = 0; oi < 4; oi++) {
    const float ts = red[0][oi] + red[1][oi] + red[2][oi] + red[3][oi];
    const float tq = red[0][4 + oi] + red[1][4 + oi] + red[2][4 + oi] + red[3][4 + oi];
    const float mu = ts * inv;
    const float var = tq * inv - mu * mu;
    const float rs = rsqrtf(var + 1e-5f);
    unsigned short* op = ynorm + (size_t)(b * 1024 + n0 + oi) * C_;
    #pragma unroll
    for (int ci = 0; ci < 3; ci++) {
      const int c = t + (ci << 8);
      op[c] = f2bf((v[ci][oi] - mu) * rs * lnw[c] + lnb[c]);
    }
  }
}

// ---------------- LDS-staged GEMM core: 128x64 wg tile, BK=64, XOR-swizzled LDS ----------
// stage ROWSx64 bf16 tile via global_load_lds w=16; LDS rows 128B, koff ^= (r&7)<<4.
// Linear LDS dest + inverse-swizzled global source (guide §5 rule 21).
template <int ROWS>
__device__ __forceinline__ void stage_tile(const unsigned short* __restrict__ src,
                                           unsigned short* lds, int tid) {
  #pragma unroll
  for (int c = 0; c < ROWS / 32; c++) {
    const int lin = c * 4096 + (tid >> 6) * 1024 + (tid & 63) * 16;  // linear byte
    const int r = lin >> 7;
    const int koff = (lin & 127) ^ ((r & 7) << 4);
    const char* g = (const char*)(src + (size_t)r * 768) + koff;
    __builtin_amdgcn_global_load_lds(
        (const __attribute__((address_space(1))) uint32_t*)g,
        (__attribute__((address_space(3))) uint32_t*)(lds + (c * 2048 + (tid >> 6) * 512)),
        16, 0, 0);
  }
}

__device__ __forceinline__ void gemm_core(const unsigned short* __restrict__ A,
                                          const unsigned short* __restrict__ BT,
                                          int m0, int n0,
                                          unsigned short* Alds, unsigned short* Blds,
                                          f32x4 (&acc)[4][2]) {
  const int tid = threadIdx.x;
  const int l = tid & 63, w = tid >> 6;
  const int lr = l & 15, lk = l >> 4;
  const int wm = (w >> 1) * 64, wn = (w & 1) * 32;
  #pragma unroll
  for (int i = 0; i < 4; i++)
    #pragma unroll
    for (int j = 0; j < 2; j++) acc[i][j] = (f32x4){0.f, 0.f, 0.f, 0.f};

  for (int kt = 0; kt < 768; kt += 64) {
    __syncthreads();  // previous tile fully consumed
    stage_tile<128>(A + (size_t)m0 * 768 + kt, Alds, tid);
    stage_tile<64>(BT + (size_t)n0 * 768 + kt, Blds, tid);
    asm volatile("s_waitcnt vmcnt(0)" ::: "memory");
    __syncthreads();
    #pragma unroll
    for (int s = 0; s < 2; s++) {
      bf16x8 a[4], b[2];
      #pragma unroll
      for (int i = 0; i < 4; i++) {
        const int r = wm + i * 16 + lr;
        const int byte = r * 128 + ((s * 64 + lk * 16) ^ ((r & 7) << 4));
        a[i] = *(const bf16x8*)((const char*)Alds + byte);
      }
      #pragma unroll
      for (int j = 0; j < 2; j++) {
        const int r = wn + j * 16 + lr;
        const int byte = r * 128 + ((s * 64 + lk * 16) ^ ((r & 7) << 4));
        b[j] = *(const bf16x8*)((const char*)Blds + byte);
      }
      #pragma unroll
      for (int i = 0; i < 4; i++)
        #pragma unroll
        for (int j = 0; j < 2; j++)
          acc[i][j] = __builtin_amdgcn_mfma_f32_16x16x32_bf16(a[i], b[j], acc[i][j], 0, 0, 0);
    }
  }
}

// ---------------- merged q-proj + kv-proj GEMM ----------------
__global__ __launch_bounds__(256) void gemm_qkv_kernel(
    const unsigned short* __restrict__ xbf, const unsigned short* __restrict__ ynorm,
    const unsigned short* __restrict__ qwbf, const unsigned short* __restrict__ kvwbf,
    unsigned short* __restrict__ qbuf, unsigned short* __restrict__ kbuf,
    unsigned short* __restrict__ vtbuf) {
  __shared__ unsigned short Alds[128 * 64];
  __shared__ unsigned short Blds[64 * 64];
  const int bx = blockIdx.x;
  const bool isQ = bx < 12;
  const unsigned short* A = isQ ? xbf : ynorm;
  const unsigned short* BT = isQ ? qwbf : kvwbf;
  const int n0 = (isQ ? bx : bx - 12) * 64;
  const int m0 = blockIdx.y * 128;
  f32x4 acc[4][2];
  gemm_core(A, BT, m0, n0, Alds, Blds, acc);

  const int l = threadIdx.x & 63, w = threadIdx.x >> 6;
  const int lr = l & 15, lk = l >> 4;
  const int wm = (w >> 1) * 64, wn = (w & 1) * 32;
  #pragma unroll
  for (int i = 0; i < 4; i++) {
    const int r0 = m0 + wm + i * 16 + lk * 4;
    #pragma unroll
    for (int j = 0; j < 2; j++) {
      const int c = n0 + wn + j * 16 + lr;
      if (isQ) {
        const int h = c >> 6, d = c & 63;
        #pragma unroll
        for (int g = 0; g < 4; g++) {
          const int row = r0 + g;
          const int bb = row >> 10, nn = row & 1023;
          qbuf[((((size_t)bb * H_ + h) << 10) + nn) * 64 + d] = f2bf(acc[i][j][g]);
        }
      } else if (c < C_) {
        const int h = c >> 6, d = c & 63;
        #pragma unroll
        for (int g = 0; g < 4; g++) {
          const int row = r0 + g;
          const int bb = row >> 10, nn = row & 1023;
          kbuf[((((size_t)bb * H_ + h) << 10) + nn) * 64 + d] = f2bf(acc[i][j][g]);
        }
      } else {
        const int c2 = c - C_;
        const int h = c2 >> 6, d = c2 & 63;
        const int bb = r0 >> 10, nn = r0 & 1023;  // 4 consecutive n, same b
        uint2 p;
        p.x = (uint32_t)f2bf(acc[i][j][0]) | ((uint32_t)f2bf(acc[i][j][1]) << 16);
        p.y = (uint32_t)f2bf(acc[i][j][2]) | ((uint32_t)f2bf(acc[i][j][3]) << 16);
        *(uint2*)(vtbuf + (((size_t)bb * H_ + h) * 64 + d) * 1024 + nn) = p;
      }
    }
  }
}

// ---------------- out-proj GEMM (+bias +residual, f32 out) ----------------
__global__ __launch_bounds__(256) void gemm_proj_kernel(
    const unsigned short* __restrict__ A, const unsigned short* __restrict__ BT,
    float* __restrict__ out, const float* __restrict__ bias,
    const float* __restrict__ resid) {
  __shared__ unsigned short Alds[128 * 64];
  __shared__ unsigned short Blds[64 * 64];
  const int n0 = blockIdx.x * 64;
  const int m0 = blockIdx.y * 128;
  f32x4 acc[4][2];
  gemm_core(A, BT, m0, n0, Alds, Blds, acc);

  const int l = threadIdx.x & 63, w = threadIdx.x >> 6;
  const int lr = l & 15, lk = l >> 4;
  const int wm = (w >> 1) * 64, wn = (w & 1) * 32;
  #pragma unroll
  for (int i = 0; i < 4; i++) {
    const int r0 = m0 + wm + i * 16 + lk * 4;
    #pragma unroll
    for (int j = 0; j < 2; j++) {
      const int c = n0 + wn + j * 16 + lr;
      #pragma unroll
      for (int g = 0; g < 4; g++) {
        const size_t idx = (size_t)(r0 + g) * C_ + c;
        out[idx] = acc[i][j][g] + bias[c] + resid[idx];
      }
    }
  }
}

// ---------------- fused attention: QK^T -> dual top-k softmax weights -> PV -------------
// 16 q-rows per block, 512 threads = 8 waves; W [16][1024] bf16 XOR-swizzled (32 KB).
// Scores are in log2-domain (x pre-scaled by 0.125*log2e); exp -> exp2.
__global__ __launch_bounds__(512, 8) void attn_kernel(
    const unsigned short* __restrict__ qbuf,   // [B,H,NX,64] bf16 (log2-scaled)
    const unsigned short* __restrict__ kbuf,   // [B,H,NY,64] bf16
    const unsigned short* __restrict__ vtbuf,  // [B,H,64,NY] bf16
    unsigned short* __restrict__ ao,           // [B*NX, 768] bf16
    const int* __restrict__ k1p, const int* __restrict__ k2p) {
  __shared__ unsigned short W[16 * 1024];  // 32 KB
  __shared__ float P[16 * 66];             // partial-sum combine
  const int l = threadIdx.x & 63, w = threadIdx.x >> 6;
  const int lr = l & 15, lk = l >> 4;
  const int bh = blockIdx.y, qt = blockIdx.x;
  const uint32_t kn1 = rfl(k1p[0]), kn2 = rfl(k2p[0]);  // 637, 575
  const size_t base = (size_t)bh * NY_ * 64;
  const unsigned short* Q = qbuf + base + (size_t)qt * 16 * 64;
  const unsigned short* Kp = kbuf + base;
  const unsigned short* Vt = vtbuf + base;

  // ---- Phase A: swapped QK^T. Wave w owns k-range [w*128, w*128+128). ----
  bf16x8 qf[2];
  #pragma unroll
  for (int s = 0; s < 2; s++)
    qf[s] = *(const bf16x8*)(Q + lr * 64 + s * 32 + lk * 8);

  #pragma unroll
  for (int kc = 0; kc < 2; kc++) {
    const int kbase = w * 128 + kc * 64;
    f32x4 acc[4];
    #pragma unroll
    for (int i = 0; i < 4; i++) acc[i] = (f32x4){0.f, 0.f, 0.f, 0.f};
    #pragma unroll
    for (int s = 0; s < 2; s++) {
      bf16x8 kf[4];
      #pragma unroll
      for (int i = 0; i < 4; i++)
        kf[i] = *(const bf16x8*)(Kp + (size_t)(kbase + i * 16 + lr) * 64 + s * 32 + lk * 8);
      #pragma unroll
      for (int i = 0; i < 4; i++)
        acc[i] = __builtin_amdgcn_mfma_f32_16x16x32_bf16(kf[i], qf[s], acc[i], 0, 0, 0);
    }
    #pragma unroll
    for (int i = 0; i < 4; i++) {
      const int kk = kbase + i * 16 + lk * 4;
      uint2 p;
      p.x = (uint32_t)f2bf(acc[i][0]) | ((uint32_t)f2bf(acc[i][1]) << 16);
      p.y = (uint32_t)f2bf(acc[i][2]) | ((uint32_t)f2bf(acc[i][3]) << 16);
      const int byte = lr * 2048 + ((kk * 2) ^ ((lr & 7) << 4));
      *(uint2*)((char*)W + byte) = p;
    }
  }
  __syncthreads();

  // ---- Phase B: dual exact k-th-largest + weights. Wave w owns rows 2w, 2w+1. ----
  {
    char* rpa = (char*)W + (2 * w) * 2048;
    char* rpb = rpa + 2048;
    uint4 a0 = *(uint4*)(rpa + 16 * l);
    uint4 a1 = *(uint4*)(rpa + 16 * l + 1024);
    uint4 b0 = *(uint4*)(rpb + 16 * l);
    uint4 b1 = *(uint4*)(rpb + 16 * l + 1024);
    uint32_t ka[16], kb[16];
    {
      uint32_t ua[8] = {a0.x, a0.y, a0.z, a0.w, a1.x, a1.y, a1.z, a1.w};
      uint32_t ub[8] = {b0.x, b0.y, b0.z, b0.w, b1.x, b1.y, b1.z, b1.w};
      #pragma unroll
      for (int i = 0; i < 8; i++) {
        uint32_t h0 = ua[i] & 0xFFFFu, h1 = ua[i] >> 16;
        ka[2 * i]     = h0 ^ (0x8000u | (0xFFFFu * (h0 >> 15)));
        ka[2 * i + 1] = h1 ^ (0x8000u | (0xFFFFu * (h1 >> 15)));
        h0 = ub[i] & 0xFFFFu; h1 = ub[i] >> 16;
        kb[2 * i]     = h0 ^ (0x8000u | (0xFFFFu * (h0 >> 15)));
        kb[2 * i + 1] = h1 ^ (0x8000u | (0xFFFFu * (h1 >> 15)));
      }
    }
    uint32_t kmxa = 0, kmxb = 0;
    #pragma unroll
    for (int i = 0; i < 16; i++) { kmxa = umaxu(kmxa, ka[i]); kmxb = umaxu(kmxb, kb[i]); }
    #pragma unroll
    for (int m = 32; m >= 1; m >>= 1) {
      kmxa = umaxu(kmxa, (uint32_t)__shfl_xor((int)kmxa, m));
      kmxb = umaxu(kmxb, (uint32_t)__shfl_xor((int)kmxb, m));
    }
    kmxa = rfl(kmxa); kmxb = rfl(kmxb);

    // 4 joint adaptive binary searches, all bookkeeping on SALU.
    // a1/a2 = row a thresholds for kn1/kn2; t1 <= t2 gives mutual clamps.
    uint32_t la1 = 0, ha1 = kmxa, la2 = 0, ha2 = kmxa;
    uint32_t lb1 = 0, hb1 = kmxb, lb2 = 0, hb2 = kmxb;
    while ((la1 < ha1) | (la2 < ha2) | (lb1 < hb1) | (lb2 < hb2)) {
      la2 = umaxu(la2, la1); ha1 = uminu(ha1, ha2);
      lb2 = umaxu(lb2, lb1); hb1 = uminu(hb1, hb2);
      if (la1 < ha1) {
        const uint32_t m = (la1 + ha1 + 1) >> 1; int c; COUNT16(ka, m, c);
        if ((uint32_t)c >= kn1) la1 = m; else ha1 = m - 1;
      }
      if (la2 < ha2) {
        const uint32_t m = (la2 + ha2 + 1) >> 1; int c; COUNT16(ka, m, c);
        if ((uint32_t)c >= kn2) la2 = m; else ha2 = m - 1;
      }
      if (lb1 < hb1) {
        const uint32_t m = (lb1 + hb1 + 1) >> 1; int c; COUNT16(kb, m, c);
        if ((uint32_t)c >= kn1) lb1 = m; else hb1 = m - 1;
      }
      if (lb2 < hb2) {
        const uint32_t m = (lb2 + hb2 + 1) >> 1; int c; COUNT16(kb, m, c);
        if ((uint32_t)c >= kn2) lb2 = m; else hb2 = m - 1;
      }
    }
    const uint32_t t1a = la1, t2a = la2, t1b = lb1, t2b = lb2;

    const float fmxa = bf2f(kmxa ^ ((kmxa & 0x8000u) ? 0x8000u : 0xFFFFu));
    const float fmxb = bf2f(kmxb ^ ((kmxb & 0x8000u) ? 0x8000u : 0xFFFFu));
    // pass 1: sums (top = keys>=t2, band = t1<=key<t2); scores in log2-domain -> exp2
    float topa = 0.f, banda = 0.f, topb = 0.f, bandb = 0.f;
    #pragma unroll
    for (int i = 0; i < 16; i++) {
      const uint32_t hda = ka[i] ^ ((ka[i] & 0x8000u) ? 0x8000u : 0xFFFFu);
      const uint32_t hdb = kb[i] ^ ((kb[i] & 0x8000u) ? 0x8000u : 0xFFFFu);
      const float eva = exp2_fast(bf2f(hda) - fmxa);
      const float evb = exp2_fast(bf2f(hdb) - fmxb);
      if (ka[i] >= t2a) topa += eva;
      else if (ka[i] >= t1a) banda += eva;
      if (kb[i] >= t2b) topb += evb;
      else if (kb[i] >= t1b) bandb += evb;
    }
    #pragma unroll
    for (int m = 32; m >= 1; m >>= 1) {
      topa += __shfl_xor(topa, m); banda += __shfl_xor(banda, m);
      topb += __shfl_xor(topb, m); bandb += __shfl_xor(bandb, m);
    }
    const float c1a = 0.6f / (topa + banda), c2a = 0.4f / topa;
    const float c1b = 0.6f / (topb + bandb), c2b = 0.4f / topb;
    const float c12a = c1a + c2a, c12b = c1b + c2b;
    // pass 2: weights (recompute exp2; keeps VGPR <= 64)
    uint32_t oa[8], ob[8];
    #pragma unroll
    for (int i = 0; i < 8; i++) {
      const int i0 = 2 * i, i1 = 2 * i + 1;
      const uint32_t ha0 = ka[i0] ^ ((ka[i0] & 0x8000u) ? 0x8000u : 0xFFFFu);
      const uint32_t ha1_ = ka[i1] ^ ((ka[i1] & 0x8000u) ? 0x8000u : 0xFFFFu);
      const uint32_t hb0 = kb[i0] ^ ((kb[i0] & 0x8000u) ? 0x8000u : 0xFFFFu);
      const uint32_t hb1_ = kb[i1] ^ ((kb[i1] & 0x8000u) ? 0x8000u : 0xFFFFu);
      const float ca0 = (ka[i0] >= t1a) ? ((ka[i0] >= t2a) ? c12a : c1a) : 0.f;
      const float ca1 = (ka[i1] >= t1a) ? ((ka[i1] >= t2a) ? c12a : c1a) : 0.f;
      const float cb0 = (kb[i0] >= t1b) ? ((kb[i0] >= t2b) ? c12b : c1b) : 0.f;
      const float cb1 = (kb[i1] >= t1b) ? ((kb[i1] >= t2b) ? c12b : c1b) : 0.f;
      const float wa0 = exp2_fast(bf2f(ha0) - fmxa) * ca0;
      const float wa1 = exp2_fast(bf2f(ha1_) - fmxa) * ca1;
      const float wb0 = exp2_fast(bf2f(hb0) - fmxb) * cb0;
      const float wb1 = exp2_fast(bf2f(hb1_) - fmxb) * cb1;
      oa[i] = (uint32_t)f2bf(wa0) | ((uint32_t)f2bf(wa1) << 16);
      ob[i] = (uint32_t)f2bf(wb0) | ((uint32_t)f2bf(wb1) << 16);
    }
    *(uint4*)(rpa + 16 * l)        = (uint4){oa[0], oa[1], oa[2], oa[3]};
    *(uint4*)(rpa + 16 * l + 1024) = (uint4){oa[4], oa[5], oa[6], oa[7]};
    *(uint4*)(rpb + 16 * l)        = (uint4){ob[0], ob[1], ob[2], ob[3]};
    *(uint4*)(rpb + 16 * l + 1024) = (uint4){ob[4], ob[5], ob[6], ob[7]};
  }
  __syncthreads();

  // ---- Phase C: PV, k-split across wave halves. d-block = (w&3)*16, k-half = w>>2. ----
  const int d0 = (w & 3) * 16;
  const int k0 = (w >> 2) * 512;
  f32x4 oacc = (f32x4){0.f, 0.f, 0.f, 0.f};
  #pragma unroll 4
  for (int kt2 = 0; kt2 < 512; kt2 += 32) {
    const int kt = k0 + kt2;
    const bf16x8 vf = *(const bf16x8*)(Vt + (size_t)(d0 + lr) * 1024 + kt + lk * 8);
    const int byte = lr * 2048 + (((kt + lk * 8) * 2) ^ ((lr & 7) << 4));
    const bf16x8 wf = *(const bf16x8*)((char*)W + byte);
    oacc = __builtin_amdgcn_mfma_f32_16x16x32_bf16(wf, vf, oacc, 0, 0, 0);
  }
  if (w >= 4) {
    #pragma unroll
    for (int g = 0; g < 4; g++)
      P[(lk * 4 + g) * 66 + d0 + lr] = oacc[g];
  }
  __syncthreads();
  if (w < 4) {
    const int b = bh / H_, h = bh % H_;
    #pragma unroll
    for (int g = 0; g < 4; g++) {
      const float v = oacc[g] + P[(lk * 4 + g) * 66 + d0 + lr];
      const int qrow = qt * 16 + lk * 4 + g;
      ao[(size_t)(b * NX_ + qrow) * C_ + h * 64 + d0 + lr] = f2bf(v);
    }
  }
}

// ---------------- launch ----------------
extern "C" void kernel_launch(void* const* d_in, const int* in_sizes, int n_in,
                              void* d_out, int out_size, void* d_ws, size_t ws_size,
                              hipStream_t stream) {
  const float* x   = (const float*)d_in[0];
  const float* y   = (const float*)d_in[1];
  const float* w1  = (const float*)d_in[2];
  const float* b1  = (const float*)d_in[3];
  const float* w2  = (const float*)d_in[4];
  const float* b2  = (const float*)d_in[5];
  const float* w3  = (const float*)d_in[6];
  const float* b3  = (const float*)d_in[7];
  const float* lnw = (const float*)d_in[8];
  const float* lnb = (const float*)d_in[9];
  const float* qw  = (const float*)d_in[10];
  const float* kvw = (const float*)d_in[11];
  const float* pw  = (const float*)d_in[12];
  const float* pb  = (const float*)d_in[13];
  const int* k1p   = (const int*)d_in[14];
  const int* k2p   = (const int*)d_in[15];

  char* ws = (char*)d_ws;
  size_t off = 0;
  auto alloc = [&](size_t bytes) {
    char* p = ws + off;
    off += (bytes + 255) & ~(size_t)255;
    return p;
  };
  const size_t NTOK = (size_t)B_ * NX_ * C_;
  unsigned short* x_bf   = (unsigned short*)alloc(NTOK * 2);
  unsigned short* ynorm  = (unsigned short*)alloc(NTOK * 2);
  unsigned short* qw_bf  = (unsigned short*)alloc((size_t)C_ * C_ * 2);
  unsigned short* kvw_bf = (unsigned short*)alloc((size_t)2 * C_ * C_ * 2);
  unsigned short* pw_bf  = (unsigned short*)alloc((size_t)C_ * C_ * 2);
  unsigned short* qbuf   = (unsigned short*)alloc(NTOK * 2);
  unsigned short* kbuf   = (unsigned short*)alloc(NTOK * 2);
  unsigned short* vtbuf  = (unsigned short*)alloc(NTOK * 2);
  unsigned short* aobuf  = (unsigned short*)alloc(NTOK * 2);

  pre_kernel<<<6400, 256, 0, stream>>>(
      y, w1, b1, w2, b2, w3, b3, lnw, lnb, ynorm,
      (const float4*)x, (uint2*)x_bf, (const float4*)qw, (uint2*)qw_bf,
      (const float4*)kvw, (uint2*)kvw_bf, (const float4*)pw, (uint2*)pw_bf);

  gemm_qkv_kernel<<<dim3(36, 32), 256, 0, stream>>>(
      x_bf, ynorm, qw_bf, kvw_bf, qbuf, kbuf, vtbuf);

  attn_kernel<<<dim3(NX_ / 16, B_ * H_), 512, 0, stream>>>(qbuf, kbuf, vtbuf, aobuf, k1p, k2p);

  gemm_proj_kernel<<<dim3(12, 32), 256, 0, stream>>>(
      aobuf, pw_bf, (float*)d_out, pb, x);
}

// Round 7
// 295.051 us; speedup vs baseline: 1.6291x; 1.0561x over previous
//
#include <hip/hip_runtime.h>
#include <stdint.h>

#define B_ 4
#define NX_ 1024
#define NY_ 1024
#define C_ 768
#define H_ 12

using bf16x8 = __attribute__((ext_vector_type(8))) short;
using f32x4  = __attribute__((ext_vector_type(4))) float;

__device__ __forceinline__ unsigned short f2bf(float f) {
  union { float f; uint32_t u; } v; v.f = f;
  return (unsigned short)((v.u + 0x7FFFu + ((v.u >> 16) & 1u)) >> 16);  // RNE
}
__device__ __forceinline__ float bf2f(uint32_t h) {
  union { uint32_t u; float f; } v; v.u = h << 16;
  return v.f;
}
__device__ __forceinline__ uint32_t umaxu(uint32_t a, uint32_t b) { return a > b ? a : b; }
__device__ __forceinline__ uint32_t uminu(uint32_t a, uint32_t b) { return a < b ? a : b; }
__device__ __forceinline__ uint32_t rfl(uint32_t v) {
  return (uint32_t)__builtin_amdgcn_readfirstlane((int)v);
}
// order-preserving 16-bit key <-> bf16 value
__device__ __forceinline__ uint32_t key2h(uint32_t k) {
  return k ^ ((k & 0x8000u) ? 0x8000u : 0xFFFFu);
}
__device__ __forceinline__ float key2f(uint32_t k) { return bf2f(key2h(k)); }
__device__ __forceinline__ uint32_t f2key(float f) {
  const uint32_t h = f2bf(f);
  return h ^ (0x8000u | (0xFFFFu * (h >> 15)));
}

// ---------------- fused pre: conv+LN (blocks 0..1023) + casts (blocks 1024..6399) ----------
__global__ __launch_bounds__(256) void pre_kernel(
    const float* __restrict__ y,
    const float* __restrict__ w1, const float* __restrict__ b1,
    const float* __restrict__ w2, const float* __restrict__ b2,
    const float* __restrict__ w3, const float* __restrict__ b3,
    const float* __restrict__ lnw, const float* __restrict__ lnb,
    unsigned short* __restrict__ ynorm,
    const float4* __restrict__ x, uint2* __restrict__ xo,
    const float4* __restrict__ qw, uint2* __restrict__ qo,
    const float4* __restrict__ kvw, uint2* __restrict__ kvo,
    const float4* __restrict__ pw, uint2* __restrict__ po) {
  __shared__ float red[4][8];
  const int bid = blockIdx.x;
  const int t = threadIdx.x;
  if (bid >= 1024) {
    // ---- cast part. x scaled by (1/8)*log2(e): scores land in log2-domain. ----
    const int cid = bid - 1024;
    const float4* s; uint2* d; int base; float sc = 1.0f;
    if (cid < 3072)      { s = x;   d = xo;  base = cid;        sc = 0.125f * 1.44269504f; }
    else if (cid < 3648) { s = qw;  d = qo;  base = cid - 3072; }
    else if (cid < 4800) { s = kvw; d = kvo; base = cid - 3648; }
    else                 { s = pw;  d = po;  base = cid - 4800; }
    const int i = base * 256 + t;
    float4 v = s[i];
    uint2 p;
    p.x = (uint32_t)f2bf(v.x * sc) | ((uint32_t)f2bf(v.y * sc) << 16);
    p.y = (uint32_t)f2bf(v.z * sc) | ((uint32_t)f2bf(v.w * sc) << 16);
    d[i] = p;
    return;
  }
  // ---- conv + LN part: 4 consecutive n per block ----
  const int b = bid >> 8, n0 = (bid & 255) << 2;
  const float* yb = y + (size_t)b * NY_ * C_;
  float v[3][4];
  #pragma unroll
  for (int ci = 0; ci < 3; ci++) {
    const int c = t + (ci << 8);
    float co[7];
    #pragma unroll
    for (int k = 0; k < 7; k++) co[k] = w3[c * 7 + k];
    #pragma unroll
    for (int k = 0; k < 5; k++) co[k + 1] += w2[c * 5 + k];
    #pragma unroll
    for (int k = 0; k < 3; k++) co[k + 2] += w1[c * 3 + k];
    const float bias = b1[c] + b2[c] + b3[c];
    float rv[10];
    #pragma unroll
    for (int rr = 0; rr < 10; rr++) {
      const int nn = n0 - 3 + rr;
      rv[rr] = (nn >= 0 && nn < NY_) ? yb[(size_t)nn * C_ + c] : 0.0f;
    }
    #pragma unroll
    for (int oi = 0; oi < 4; oi++) {
      float acc = bias;
      #pragma unroll
      for (int k = 0; k < 7; k++) acc = fmaf(co[k], rv[oi + k], acc);
      v[ci][oi] = acc;
    }
  }
  float s4[4], q4[4];
  #pragma unroll
  for (int oi = 0; oi < 4; oi++) {
    s4[oi] = v[0][oi] + v[1][oi] + v[2][oi];
    q4[oi] = v[0][oi] * v[0][oi] + v[1][oi] * v[1][oi] + v[2][oi] * v[2][oi];
  }
  #pragma unroll
  for (int m = 32; m >= 1; m >>= 1) {
    #pragma unroll
    for (int oi = 0; oi < 4; oi++) {
      s4[oi] += __shfl_xor(s4[oi], m);
      q4[oi] += __shfl_xor(q4[oi], m);
    }
  }
  const int wid = t >> 6;
  if ((t & 63) == 0) {
    #pragma unroll
    for (int oi = 0; oi < 4; oi++) { red[wid][oi] = s4[oi]; red[wid][4 + oi] = q4[oi]; }
  }
  __syncthreads();
  const float inv = 1.0f / 768.0f;
  #pragma unroll
  for (int oi = 0; oi < 4; oi++) {
    const float ts = red[0][oi] + red[1][oi] + red[2][oi] + red[3][oi];
    const float tq = red[0][4 + oi] + red[1][4 + oi] + red[2][4 + oi] + red[3][4 + oi];
    const float mu = ts * inv;
    const float var = tq * inv - mu * mu;
    const float rs = rsqrtf(var + 1e-5f);
    unsigned short* op = ynorm + (size_t)(b * 1024 + n0 + oi) * C_;
    #pragma unroll
    for (int ci = 0; ci < 3; ci++) {
      const int c = t + (ci << 8);
      op[c] = f2bf((v[ci][oi] - mu) * rs * lnw[c] + lnb[c]);
    }
  }
}

// ---------------- LDS-staged GEMM core: 128x64 wg tile, BK=64, XOR-swizzled LDS ----------
template <int ROWS>
__device__ __forceinline__ void stage_tile(const unsigned short* __restrict__ src,
                                           unsigned short* lds, int tid) {
  #pragma unroll
  for (int c = 0; c < ROWS / 32; c++) {
    const int lin = c * 4096 + (tid >> 6) * 1024 + (tid & 63) * 16;  // linear byte
    const int r = lin >> 7;
    const int koff = (lin & 127) ^ ((r & 7) << 4);
    const char* g = (const char*)(src + (size_t)r * 768) + koff;
    __builtin_amdgcn_global_load_lds(
        (const __attribute__((address_space(1))) uint32_t*)g,
        (__attribute__((address_space(3))) uint32_t*)(lds + (c * 2048 + (tid >> 6) * 512)),
        16, 0, 0);
  }
}

__device__ __forceinline__ void gemm_core(const unsigned short* __restrict__ A,
                                          const unsigned short* __restrict__ BT,
                                          int m0, int n0,
                                          unsigned short* Alds, unsigned short* Blds,
                                          f32x4 (&acc)[4][2]) {
  const int tid = threadIdx.x;
  const int l = tid & 63, w = tid >> 6;
  const int lr = l & 15, lk = l >> 4;
  const int wm = (w >> 1) * 64, wn = (w & 1) * 32;
  #pragma unroll
  for (int i = 0; i < 4; i++)
    #pragma unroll
    for (int j = 0; j < 2; j++) acc[i][j] = (f32x4){0.f, 0.f, 0.f, 0.f};

  for (int kt = 0; kt < 768; kt += 64) {
    __syncthreads();  // previous tile fully consumed
    stage_tile<128>(A + (size_t)m0 * 768 + kt, Alds, tid);
    stage_tile<64>(BT + (size_t)n0 * 768 + kt, Blds, tid);
    asm volatile("s_waitcnt vmcnt(0)" ::: "memory");
    __syncthreads();
    #pragma unroll
    for (int s = 0; s < 2; s++) {
      bf16x8 a[4], b[2];
      #pragma unroll
      for (int i = 0; i < 4; i++) {
        const int r = wm + i * 16 + lr;
        const int byte = r * 128 + ((s * 64 + lk * 16) ^ ((r & 7) << 4));
        a[i] = *(const bf16x8*)((const char*)Alds + byte);
      }
      #pragma unroll
      for (int j = 0; j < 2; j++) {
        const int r = wn + j * 16 + lr;
        const int byte = r * 128 + ((s * 64 + lk * 16) ^ ((r & 7) << 4));
        b[j] = *(const bf16x8*)((const char*)Blds + byte);
      }
      #pragma unroll
      for (int i = 0; i < 4; i++)
        #pragma unroll
        for (int j = 0; j < 2; j++)
          acc[i][j] = __builtin_amdgcn_mfma_f32_16x16x32_bf16(a[i], b[j], acc[i][j], 0, 0, 0);
    }
  }
}

// ---------------- merged q-proj + kv-proj GEMM ----------------
__global__ __launch_bounds__(256) void gemm_qkv_kernel(
    const unsigned short* __restrict__ xbf, const unsigned short* __restrict__ ynorm,
    const unsigned short* __restrict__ qwbf, const unsigned short* __restrict__ kvwbf,
    unsigned short* __restrict__ qbuf, unsigned short* __restrict__ kbuf,
    unsigned short* __restrict__ vtbuf) {
  __shared__ unsigned short Alds[128 * 64];
  __shared__ unsigned short Blds[64 * 64];
  const int bx = blockIdx.x;
  const bool isQ = bx < 12;
  const unsigned short* A = isQ ? xbf : ynorm;
  const unsigned short* BT = isQ ? qwbf : kvwbf;
  const int n0 = (isQ ? bx : bx - 12) * 64;
  const int m0 = blockIdx.y * 128;
  f32x4 acc[4][2];
  gemm_core(A, BT, m0, n0, Alds, Blds, acc);

  const int l = threadIdx.x & 63, w = threadIdx.x >> 6;
  const int lr = l & 15, lk = l >> 4;
  const int wm = (w >> 1) * 64, wn = (w & 1) * 32;
  #pragma unroll
  for (int i = 0; i < 4; i++) {
    const int r0 = m0 + wm + i * 16 + lk * 4;
    #pragma unroll
    for (int j = 0; j < 2; j++) {
      const int c = n0 + wn + j * 16 + lr;
      if (isQ) {
        const int h = c >> 6, d = c & 63;
        #pragma unroll
        for (int g = 0; g < 4; g++) {
          const int row = r0 + g;
          const int bb = row >> 10, nn = row & 1023;
          qbuf[((((size_t)bb * H_ + h) << 10) + nn) * 64 + d] = f2bf(acc[i][j][g]);
        }
      } else if (c < C_) {
        const int h = c >> 6, d = c & 63;
        #pragma unroll
        for (int g = 0; g < 4; g++) {
          const int row = r0 + g;
          const int bb = row >> 10, nn = row & 1023;
          kbuf[((((size_t)bb * H_ + h) << 10) + nn) * 64 + d] = f2bf(acc[i][j][g]);
        }
      } else {
        const int c2 = c - C_;
        const int h = c2 >> 6, d = c2 & 63;
        const int bb = r0 >> 10, nn = r0 & 1023;  // 4 consecutive n, same b
        uint2 p;
        p.x = (uint32_t)f2bf(acc[i][j][0]) | ((uint32_t)f2bf(acc[i][j][1]) << 16);
        p.y = (uint32_t)f2bf(acc[i][j][2]) | ((uint32_t)f2bf(acc[i][j][3]) << 16);
        *(uint2*)(vtbuf + (((size_t)bb * H_ + h) * 64 + d) * 1024 + nn) = p;
      }
    }
  }
}

// ---------------- out-proj GEMM (+bias +residual, f32 out) ----------------
__global__ __launch_bounds__(256) void gemm_proj_kernel(
    const unsigned short* __restrict__ A, const unsigned short* __restrict__ BT,
    float* __restrict__ out, const float* __restrict__ bias,
    const float* __restrict__ resid) {
  __shared__ unsigned short Alds[128 * 64];
  __shared__ unsigned short Blds[64 * 64];
  const int n0 = blockIdx.x * 64;
  const int m0 = blockIdx.y * 128;
  f32x4 acc[4][2];
  gemm_core(A, BT, m0, n0, Alds, Blds, acc);

  const int l = threadIdx.x & 63, w = threadIdx.x >> 6;
  const int lr = l & 15, lk = l >> 4;
  const int wm = (w >> 1) * 64, wn = (w & 1) * 32;
  #pragma unroll
  for (int i = 0; i < 4; i++) {
    const int r0 = m0 + wm + i * 16 + lk * 4;
    #pragma unroll
    for (int j = 0; j < 2; j++) {
      const int c = n0 + wn + j * 16 + lr;
      #pragma unroll
      for (int g = 0; g < 4; g++) {
        const size_t idx = (size_t)(r0 + g) * C_ + c;
        out[idx] = acc[i][j][g] + bias[c] + resid[idx];
      }
    }
  }
}

// ---- exact-bracket secant/bisect threshold search (all-VALU counting) ----
// invariant: count(>=lo) = clo >= kn; count(>=hi) = chi < kn. Accept when
// clo-kn <= 8 (near-threshold weights ~5e-4 each) or bracket closed.
struct SR { uint32_t t; uint32_t c; };
__device__ __forceinline__ SR searchk(const uint32_t (&k)[16], uint32_t kn,
                                      uint32_t lo, uint32_t clo, float flo,
                                      uint32_t hi, float fhi) {
  uint32_t chi = 0;
  #pragma unroll 1
  for (int it = 0; it < 16; ++it) {
    const int active = (clo > kn + 8u) && (lo + 1u < hi);
    if (!__builtin_amdgcn_readfirstlane(active)) break;
    uint32_t tk;
    if (it & 1) {
      tk = (lo + hi) >> 1;  // bisection in key space (guaranteed progress)
    } else {               // secant on (float value, count) pairs
      const float tf = flo + (fhi - flo) * (float)(clo - kn) / (float)(clo - chi);
      tk = f2key(tf);
    }
    tk = uminu(umaxu(tk, lo + 1u), hi - 1u);
    uint32_t cnt = 0;
    #pragma unroll
    for (int i = 0; i < 16; i++) cnt += (k[i] >= tk) ? 1u : 0u;
    #pragma unroll
    for (int m = 32; m >= 1; m >>= 1) cnt += (uint32_t)__shfl_xor((int)cnt, m);
    const float tfk = key2f(tk);
    if (cnt >= kn) { lo = tk; clo = cnt; flo = tfk; }
    else           { hi = tk; chi = cnt; fhi = tfk; }
  }
  return {lo, clo};
}

// ---------------- fused attention: QK^T -> dual top-k softmax weights -> PV -------------
// 16 q-rows per block, 512 threads = 8 waves; W [16][1024] bf16 XOR-swizzled (32 KB).
// Scores are in log2-domain (x pre-scaled by 0.125*log2e); exp -> exp2.
__global__ __launch_bounds__(512, 8) void attn_kernel(
    const unsigned short* __restrict__ qbuf,   // [B,H,NX,64] bf16 (log2-scaled)
    const unsigned short* __restrict__ kbuf,   // [B,H,NY,64] bf16
    const unsigned short* __restrict__ vtbuf,  // [B,H,64,NY] bf16
    unsigned short* __restrict__ ao,           // [B*NX, 768] bf16
    const int* __restrict__ k1p, const int* __restrict__ k2p) {
  __shared__ unsigned short W[16 * 1024];  // 32 KB
  __shared__ float P[16 * 66];             // partial-sum combine
  const int l = threadIdx.x & 63, w = threadIdx.x >> 6;
  const int lr = l & 15, lk = l >> 4;
  const int bh = blockIdx.y, qt = blockIdx.x;
  const uint32_t kn1 = rfl(k1p[0]), kn2 = rfl(k2p[0]);  // 637, 575
  const size_t base = (size_t)bh * NY_ * 64;
  const unsigned short* Q = qbuf + base + (size_t)qt * 16 * 64;
  const unsigned short* Kp = kbuf + base;
  const unsigned short* Vt = vtbuf + base;

  // ---- Phase A: swapped QK^T. Wave w owns k-range [w*128, w*128+128). ----
  bf16x8 qf[2];
  #pragma unroll
  for (int s = 0; s < 2; s++)
    qf[s] = *(const bf16x8*)(Q + lr * 64 + s * 32 + lk * 8);

  #pragma unroll
  for (int kc = 0; kc < 2; kc++) {
    const int kbase = w * 128 + kc * 64;
    f32x4 acc[4];
    #pragma unroll
    for (int i = 0; i < 4; i++) acc[i] = (f32x4){0.f, 0.f, 0.f, 0.f};
    #pragma unroll
    for (int s = 0; s < 2; s++) {
      bf16x8 kf[4];
      #pragma unroll
      for (int i = 0; i < 4; i++)
        kf[i] = *(const bf16x8*)(Kp + (size_t)(kbase + i * 16 + lr) * 64 + s * 32 + lk * 8);
      #pragma unroll
      for (int i = 0; i < 4; i++)
        acc[i] = __builtin_amdgcn_mfma_f32_16x16x32_bf16(kf[i], qf[s], acc[i], 0, 0, 0);
    }
    #pragma unroll
    for (int i = 0; i < 4; i++) {
      const int kk = kbase + i * 16 + lk * 4;
      uint2 p;
      p.x = (uint32_t)f2bf(acc[i][0]) | ((uint32_t)f2bf(acc[i][1]) << 16);
      p.y = (uint32_t)f2bf(acc[i][2]) | ((uint32_t)f2bf(acc[i][3]) << 16);
      const int byte = lr * 2048 + ((kk * 2) ^ ((lr & 7) << 4));
      *(uint2*)((char*)W + byte) = p;
    }
  }
  __syncthreads();

  // ---- Phase B: dual k-th-largest + weights. Wave w owns rows 2w, 2w+1 (serial). ----
  #pragma unroll 1
  for (int rr = 0; rr < 2; rr++) {
    char* rp = (char*)W + (2 * w + rr) * 2048;
    const uint4 u0 = *(uint4*)(rp + 16 * l);
    const uint4 u1 = *(uint4*)(rp + 16 * l + 1024);
    uint32_t k[16];
    {
      const uint32_t uu[8] = {u0.x, u0.y, u0.z, u0.w, u1.x, u1.y, u1.z, u1.w};
      #pragma unroll
      for (int i = 0; i < 8; i++) {
        const uint32_t h0 = uu[i] & 0xFFFFu, h1 = uu[i] >> 16;
        k[2 * i]     = h0 ^ (0x8000u | (0xFFFFu * (h0 >> 15)));
        k[2 * i + 1] = h1 ^ (0x8000u | (0xFFFFu * (h1 >> 15)));
      }
    }
    uint32_t kmx = 0;
    #pragma unroll
    for (int i = 0; i < 16; i++) kmx = umaxu(kmx, k[i]);
    #pragma unroll
    for (int m = 32; m >= 1; m >>= 1)
      kmx = umaxu(kmx, (uint32_t)__shfl_xor((int)kmx, m));
    const float fmx = key2f(kmx);

    const SR r1 = searchk(k, kn1, 0u, 1024u, fmx - 12.0f, kmx + 1u, fmx);
    const SR r2 = searchk(k, kn2, r1.t, r1.c, key2f(r1.t), kmx + 1u, fmx);
    const uint32_t t1 = r1.t, t2 = r2.t;

    // pass 1: sums (top = keys>=t2, band = t1<=key<t2)
    float top = 0.f, band = 0.f;
    #pragma unroll
    for (int i = 0; i < 16; i++) {
      const float e = exp2f(key2f(k[i]) - fmx);
      if (k[i] >= t2) top += e;
      else if (k[i] >= t1) band += e;
    }
    #pragma unroll
    for (int m = 32; m >= 1; m >>= 1) {
      top += __shfl_xor(top, m);
      band += __shfl_xor(band, m);
    }
    const float c1 = 0.6f / (top + band), c2 = 0.4f / top;
    const float c12 = c1 + c2;
    // pass 2: weights (recompute exp2; register-lean)
    uint32_t o[8];
    #pragma unroll
    for (int i = 0; i < 8; i++) {
      const int i0 = 2 * i, i1 = 2 * i + 1;
      const float cf0 = (k[i0] >= t1) ? ((k[i0] >= t2) ? c12 : c1) : 0.f;
      const float cf1 = (k[i1] >= t1) ? ((k[i1] >= t2) ? c12 : c1) : 0.f;
      const float w0 = exp2f(key2f(k[i0]) - fmx) * cf0;
      const float w1 = exp2f(key2f(k[i1]) - fmx) * cf1;
      o[i] = (uint32_t)f2bf(w0) | ((uint32_t)f2bf(w1) << 16);
    }
    *(uint4*)(rp + 16 * l)        = (uint4){o[0], o[1], o[2], o[3]};
    *(uint4*)(rp + 16 * l + 1024) = (uint4){o[4], o[5], o[6], o[7]};
  }
  __syncthreads();

  // ---- Phase C: PV, k-split across wave halves. d-block = (w&3)*16, k-half = w>>2. ----
  const int d0 = (w & 3) * 16;
  const int k0 = (w >> 2) * 512;
  f32x4 oacc = (f32x4){0.f, 0.f, 0.f, 0.f};
  #pragma unroll 4
  for (int kt2 = 0; kt2 < 512; kt2 += 32) {
    const int kt = k0 + kt2;
    const bf16x8 vf = *(const bf16x8*)(Vt + (size_t)(d0 + lr) * 1024 + kt + lk * 8);
    const int byte = lr * 2048 + (((kt + lk * 8) * 2) ^ ((lr & 7) << 4));
    const bf16x8 wf = *(const bf16x8*)((char*)W + byte);
    oacc = __builtin_amdgcn_mfma_f32_16x16x32_bf16(wf, vf, oacc, 0, 0, 0);
  }
  if (w >= 4) {
    #pragma unroll
    for (int g = 0; g < 4; g++)
      P[(lk * 4 + g) * 66 + d0 + lr] = oacc[g];
  }
  __syncthreads();
  if (w < 4) {
    const int b = bh / H_, h = bh % H_;
    #pragma unroll
    for (int g = 0; g < 4; g++) {
      const float v = oacc[g] + P[(lk * 4 + g) * 66 + d0 + lr];
      const int qrow = qt * 16 + lk * 4 + g;
      ao[(size_t)(b * NX_ + qrow) * C_ + h * 64 + d0 + lr] = f2bf(v);
    }
  }
}

// ---------------- launch ----------------
extern "C" void kernel_launch(void* const* d_in, const int* in_sizes, int n_in,
                              void* d_out, int out_size, void* d_ws, size_t ws_size,
                              hipStream_t stream) {
  const float* x   = (const float*)d_in[0];
  const float* y   = (const float*)d_in[1];
  const float* w1  = (const float*)d_in[2];
  const float* b1  = (const float*)d_in[3];
  const float* w2  = (const float*)d_in[4];
  const float* b2  = (const float*)d_in[5];
  const float* w3  = (const float*)d_in[6];
  const float* b3  = (const float*)d_in[7];
  const float* lnw = (const float*)d_in[8];
  const float* lnb = (const float*)d_in[9];
  const float* qw  = (const float*)d_in[10];
  const float* kvw = (const float*)d_in[11];
  const float* pw  = (const float*)d_in[12];
  const float* pb  = (const float*)d_in[13];
  const int* k1p   = (const int*)d_in[14];
  const int* k2p   = (const int*)d_in[15];

  char* ws = (char*)d_ws;
  size_t off = 0;
  auto alloc = [&](size_t bytes) {
    char* p = ws + off;
    off += (bytes + 255) & ~(size_t)255;
    return p;
  };
  const size_t NTOK = (size_t)B_ * NX_ * C_;
  unsigned short* x_bf   = (unsigned short*)alloc(NTOK * 2);
  unsigned short* ynorm  = (unsigned short*)alloc(NTOK * 2);
  unsigned short* qw_bf  = (unsigned short*)alloc((size_t)C_ * C_ * 2);
  unsigned short* kvw_bf = (unsigned short*)alloc((size_t)2 * C_ * C_ * 2);
  unsigned short* pw_bf  = (unsigned short*)alloc((size_t)C_ * C_ * 2);
  unsigned short* qbuf   = (unsigned short*)alloc(NTOK * 2);
  unsigned short* kbuf   = (unsigned short*)alloc(NTOK * 2);
  unsigned short* vtbuf  = (unsigned short*)alloc(NTOK * 2);
  unsigned short* aobuf  = (unsigned short*)alloc(NTOK * 2);

  pre_kernel<<<6400, 256, 0, stream>>>(
      y, w1, b1, w2, b2, w3, b3, lnw, lnb, ynorm,
      (const float4*)x, (uint2*)x_bf, (const float4*)qw, (uint2*)qw_bf,
      (const float4*)kvw, (uint2*)kvw_bf, (const float4*)pw, (uint2*)pw_bf);

  gemm_qkv_kernel<<<dim3(36, 32), 256, 0, stream>>>(
      x_bf, ynorm, qw_bf, kvw_bf, qbuf, kbuf, vtbuf);

  attn_kernel<<<dim3(NX_ / 16, B_ * H_), 512, 0, stream>>>(qbuf, kbuf, vtbuf, aobuf, k1p, k2p);

  gemm_proj_kernel<<<dim3(12, 32), 256, 0, stream>>>(
      aobuf, pw_bf, (float*)d_out, pb, x);
}

// Round 9
// 270.237 us; speedup vs baseline: 1.7787x; 1.0918x over previous
//
#include <hip/hip_runtime.h>
#include <stdint.h>

#define B_ 4
#define NX_ 1024
#define NY_ 1024
#define C_ 768
#define H_ 12

using bf16x8 = __attribute__((ext_vector_type(8))) short;
using f32x4  = __attribute__((ext_vector_type(4))) float;

__device__ __forceinline__ unsigned short f2bf(float f) {
  union { float f; uint32_t u; } v; v.f = f;
  return (unsigned short)((v.u + 0x7FFFu + ((v.u >> 16) & 1u)) >> 16);  // RNE
}
__device__ __forceinline__ uint32_t rfl(uint32_t v) {
  return (uint32_t)__builtin_amdgcn_readfirstlane((int)v);
}

// ---------------- fused pre: conv+LN (blocks 0..1023) + casts (blocks 1024..6399) ----------
__global__ __launch_bounds__(256) void pre_kernel(
    const float* __restrict__ y,
    const float* __restrict__ w1, const float* __restrict__ b1,
    const float* __restrict__ w2, const float* __restrict__ b2,
    const float* __restrict__ w3, const float* __restrict__ b3,
    const float* __restrict__ lnw, const float* __restrict__ lnb,
    unsigned short* __restrict__ ynorm,
    const float4* __restrict__ x, uint2* __restrict__ xo,
    const float4* __restrict__ qw, uint2* __restrict__ qo,
    const float4* __restrict__ kvw, uint2* __restrict__ kvo,
    const float4* __restrict__ pw, uint2* __restrict__ po) {
  __shared__ float red[4][8];
  const int bid = blockIdx.x;
  const int t = threadIdx.x;
  if (bid >= 1024) {
    // cast part. x scaled by (1/8)*log2(e): scores land in log2-domain.
    const int cid = bid - 1024;
    const float4* s; uint2* d; int base; float sc = 1.0f;
    if (cid < 3072)      { s = x;   d = xo;  base = cid;        sc = 0.125f * 1.44269504f; }
    else if (cid < 3648) { s = qw;  d = qo;  base = cid - 3072; }
    else if (cid < 4800) { s = kvw; d = kvo; base = cid - 3648; }
    else                 { s = pw;  d = po;  base = cid - 4800; }
    const int i = base * 256 + t;
    float4 v = s[i];
    uint2 p;
    p.x = (uint32_t)f2bf(v.x * sc) | ((uint32_t)f2bf(v.y * sc) << 16);
    p.y = (uint32_t)f2bf(v.z * sc) | ((uint32_t)f2bf(v.w * sc) << 16);
    d[i] = p;
    return;
  }
  // conv + LN part: 4 consecutive n per block
  const int b = bid >> 8, n0 = (bid & 255) << 2;
  const float* yb = y + (size_t)b * NY_ * C_;
  float v[3][4];
  #pragma unroll
  for (int ci = 0; ci < 3; ci++) {
    const int c = t + (ci << 8);
    float co[7];
    #pragma unroll
    for (int k = 0; k < 7; k++) co[k] = w3[c * 7 + k];
    #pragma unroll
    for (int k = 0; k < 5; k++) co[k + 1] += w2[c * 5 + k];
    #pragma unroll
    for (int k = 0; k < 3; k++) co[k + 2] += w1[c * 3 + k];
    const float bias = b1[c] + b2[c] + b3[c];
    float rv[10];
    #pragma unroll
    for (int rr = 0; rr < 10; rr++) {
      const int nn = n0 - 3 + rr;
      rv[rr] = (nn >= 0 && nn < NY_) ? yb[(size_t)nn * C_ + c] : 0.0f;
    }
    #pragma unroll
    for (int oi = 0; oi < 4; oi++) {
      float acc = bias;
      #pragma unroll
      for (int k = 0; k < 7; k++) acc = fmaf(co[k], rv[oi + k], acc);
      v[ci][oi] = acc;
    }
  }
  float s4[4], q4[4];
  #pragma unroll
  for (int oi = 0; oi < 4; oi++) {
    s4[oi] = v[0][oi] + v[1][oi] + v[2][oi];
    q4[oi] = v[0][oi] * v[0][oi] + v[1][oi] * v[1][oi] + v[2][oi] * v[2][oi];
  }
  #pragma unroll
  for (int m = 32; m >= 1; m >>= 1) {
    #pragma unroll
    for (int oi = 0; oi < 4; oi++) {
      s4[oi] += __shfl_xor(s4[oi], m);
      q4[oi] += __shfl_xor(q4[oi], m);
    }
  }
  const int wid = t >> 6;
  if ((t & 63) == 0) {
    #pragma unroll
    for (int oi = 0; oi < 4; oi++) { red[wid][oi] = s4[oi]; red[wid][4 + oi] = q4[oi]; }
  }
  __syncthreads();
  const float inv = 1.0f / 768.0f;
  #pragma unroll
  for (int oi = 0; oi < 4; oi++) {
    const float ts = red[0][oi] + red[1][oi] + red[2][oi] + red[3][oi];
    const float tq = red[0][4 + oi] + red[1][4 + oi] + red[2][4 + oi] + red[3][4 + oi];
    const float mu = ts * inv;
    const float var = tq * inv - mu * mu;
    const float rs = rsqrtf(var + 1e-5f);
    unsigned short* op = ynorm + (size_t)(b * 1024 + n0 + oi) * C_;
    #pragma unroll
    for (int ci = 0; ci < 3; ci++) {
      const int c = t + (ci << 8);
      op[c] = f2bf((v[ci][oi] - mu) * rs * lnw[c] + lnb[c]);
    }
  }
}

// ---------------- LDS-staged GEMM core: 128x128 wg tile, BK=64, XOR-swizzled LDS ----------
template <int ROWS>
__device__ __forceinline__ void stage_tile(const unsigned short* __restrict__ src,
                                           unsigned short* lds, int tid) {
  #pragma unroll
  for (int c = 0; c < ROWS / 32; c++) {
    const int lin = c * 4096 + (tid >> 6) * 1024 + (tid & 63) * 16;  // linear byte
    const int r = lin >> 7;
    const int koff = (lin & 127) ^ ((r & 7) << 4);
    const char* g = (const char*)(src + (size_t)r * 768) + koff;
    __builtin_amdgcn_global_load_lds(
        (const __attribute__((address_space(1))) uint32_t*)g,
        (__attribute__((address_space(3))) uint32_t*)(lds + (c * 2048 + (tid >> 6) * 512)),
        16, 0, 0);
  }
}

// 4 waves 2x2; wave tile 64x64 (acc[4][4]); 32 MFMA per K-step per wave.
__device__ __forceinline__ void gemm_core128(const unsigned short* __restrict__ A,
                                             const unsigned short* __restrict__ BT,
                                             int m0, int n0,
                                             unsigned short* Alds, unsigned short* Blds,
                                             f32x4 (&acc)[4][4]) {
  const int tid = threadIdx.x;
  const int l = tid & 63, w = tid >> 6;
  const int lr = l & 15, lk = l >> 4;
  const int wr = (w >> 1) * 64, wc = (w & 1) * 64;
  #pragma unroll
  for (int i = 0; i < 4; i++)
    #pragma unroll
    for (int j = 0; j < 4; j++) acc[i][j] = (f32x4){0.f, 0.f, 0.f, 0.f};

  for (int kt = 0; kt < 768; kt += 64) {
    __syncthreads();  // previous tile fully consumed
    stage_tile<128>(A + (size_t)m0 * 768 + kt, Alds, tid);
    stage_tile<128>(BT + (size_t)n0 * 768 + kt, Blds, tid);
    asm volatile("s_waitcnt vmcnt(0)" ::: "memory");
    __syncthreads();
    #pragma unroll
    for (int s = 0; s < 2; s++) {
      bf16x8 a[4], b[4];
      #pragma unroll
      for (int i = 0; i < 4; i++) {
        const int r = wr + i * 16 + lr;
        const int byte = r * 128 + ((s * 64 + lk * 16) ^ ((r & 7) << 4));
        a[i] = *(const bf16x8*)((const char*)Alds + byte);
      }
      #pragma unroll
      for (int j = 0; j < 4; j++) {
        const int r = wc + j * 16 + lr;
        const int byte = r * 128 + ((s * 64 + lk * 16) ^ ((r & 7) << 4));
        b[j] = *(const bf16x8*)((const char*)Blds + byte);
      }
      #pragma unroll
      for (int i = 0; i < 4; i++)
        #pragma unroll
        for (int j = 0; j < 4; j++)
          acc[i][j] = __builtin_amdgcn_mfma_f32_16x16x32_bf16(a[i], b[j], acc[i][j], 0, 0, 0);
    }
  }
}

// ---------------- merged q-proj + kv-proj GEMM (grid.x = 18) ----------------
__global__ __launch_bounds__(256) void gemm_qkv_kernel(
    const unsigned short* __restrict__ xbf, const unsigned short* __restrict__ ynorm,
    const unsigned short* __restrict__ qwbf, const unsigned short* __restrict__ kvwbf,
    unsigned short* __restrict__ qbuf, unsigned short* __restrict__ kbuf,
    unsigned short* __restrict__ vtbuf) {
  __shared__ unsigned short Alds[128 * 64];
  __shared__ unsigned short Blds[128 * 64];
  const int bx = blockIdx.x;
  const bool isQ = bx < 6;
  const unsigned short* A = isQ ? xbf : ynorm;
  const unsigned short* BT = isQ ? qwbf : kvwbf;
  const int n0 = (isQ ? bx : bx - 6) * 128;
  const int m0 = blockIdx.y * 128;
  f32x4 acc[4][4];
  gemm_core128(A, BT, m0, n0, Alds, Blds, acc);

  const int l = threadIdx.x & 63, w = threadIdx.x >> 6;
  const int lr = l & 15, lk = l >> 4;
  const int wr = (w >> 1) * 64, wc = (w & 1) * 64;
  #pragma unroll
  for (int i = 0; i < 4; i++) {
    const int r0 = m0 + wr + i * 16 + lk * 4;
    #pragma unroll
    for (int j = 0; j < 4; j++) {
      const int c = n0 + wc + j * 16 + lr;  // col in q-space or kv-space
      if (isQ) {
        const int h = c >> 6, d = c & 63;
        #pragma unroll
        for (int g = 0; g < 4; g++) {
          const int row = r0 + g;
          const int bb = row >> 10, nn = row & 1023;
          qbuf[((((size_t)bb * H_ + h) << 10) + nn) * 64 + d] = f2bf(acc[i][j][g]);
        }
      } else if (c < C_) {
        const int h = c >> 6, d = c & 63;
        #pragma unroll
        for (int g = 0; g < 4; g++) {
          const int row = r0 + g;
          const int bb = row >> 10, nn = row & 1023;
          kbuf[((((size_t)bb * H_ + h) << 10) + nn) * 64 + d] = f2bf(acc[i][j][g]);
        }
      } else {
        const int c2 = c - C_;
        const int h = c2 >> 6, d = c2 & 63;
        const int bb = r0 >> 10, nn = r0 & 1023;  // 4 consecutive n, same b
        uint2 p;
        p.x = (uint32_t)f2bf(acc[i][j][0]) | ((uint32_t)f2bf(acc[i][j][1]) << 16);
        p.y = (uint32_t)f2bf(acc[i][j][2]) | ((uint32_t)f2bf(acc[i][j][3]) << 16);
        *(uint2*)(vtbuf + (((size_t)bb * H_ + h) * 64 + d) * 1024 + nn) = p;
      }
    }
  }
}

// ---------------- out-proj GEMM (+bias +residual, f32 out; grid.x = 6) ----------------
__global__ __launch_bounds__(256) void gemm_proj_kernel(
    const unsigned short* __restrict__ A, const unsigned short* __restrict__ BT,
    float* __restrict__ out, const float* __restrict__ bias,
    const float* __restrict__ resid) {
  __shared__ unsigned short Alds[128 * 64];
  __shared__ unsigned short Blds[128 * 64];
  const int n0 = blockIdx.x * 128;
  const int m0 = blockIdx.y * 128;
  f32x4 acc[4][4];
  gemm_core128(A, BT, m0, n0, Alds, Blds, acc);

  const int l = threadIdx.x & 63, w = threadIdx.x >> 6;
  const int lr = l & 15, lk = l >> 4;
  const int wr = (w >> 1) * 64, wc = (w & 1) * 64;
  #pragma unroll
  for (int i = 0; i < 4; i++) {
    const int r0 = m0 + wr + i * 16 + lk * 4;
    #pragma unroll
    for (int j = 0; j < 4; j++) {
      const int c = n0 + wc + j * 16 + lr;
      #pragma unroll
      for (int g = 0; g < 4; g++) {
        const size_t idx = (size_t)(r0 + g) * C_ + c;
        out[idx] = acc[i][j][g] + bias[c] + resid[idx];
      }
    }
  }
}

// ---- float-space bracketed secant/bisect k-th-largest search (all-VALU) ----
// invariant: count(>=flo)=clo>=kn ; count(>=fhi)<kn. Accepting flo includes the
// kth value's full tie group == reference top-k semantics on bf16 scores.
struct SRf { float t; uint32_t c; };
__device__ __forceinline__ SRf searchf(const float (&s)[16], uint32_t kn,
                                       float flo, uint32_t clo,
                                       float fhi, uint32_t chi, float guess) {
  float tf = guess;
  #pragma unroll 1
  for (int it = 0; it < 12; ++it) {
    if (!__builtin_amdgcn_readfirstlane((int)(clo > kn + 8u))) break;
    if (!(tf > flo && tf < fhi)) tf = 0.5f * (flo + fhi);
    uint32_t cnt = 0;
    #pragma unroll
    for (int i = 0; i < 16; i++) cnt += (s[i] >= tf) ? 1u : 0u;
    #pragma unroll
    for (int m = 32; m >= 1; m >>= 1) cnt += (uint32_t)__shfl_xor((int)cnt, m);
    if (cnt >= kn) { flo = tf; clo = cnt; }
    else           { fhi = tf; chi = cnt; }
    if (fhi - flo < 1e-3f) break;
    tf = (it & 1) ? 0.5f * (flo + fhi)
                  : flo + (fhi - flo) * (float)(int)(clo - kn) /
                        fmaxf((float)(int)(clo - chi), 1.0f);
  }
  return {flo, clo};
}

// ---------------- fused attention: QK^T -> dual top-k softmax weights -> PV -------------
// 16 q-rows/block, 8 waves; W [16][1024] bf16 XOR-swizzled (32 KB); log2-domain scores.
__global__ __launch_bounds__(512, 6) void attn_kernel(
    const unsigned short* __restrict__ qbuf,   // [B,H,NX,64] bf16 (log2-scaled)
    const unsigned short* __restrict__ kbuf,   // [B,H,NY,64] bf16
    const unsigned short* __restrict__ vtbuf,  // [B,H,64,NY] bf16
    unsigned short* __restrict__ ao,           // [B*NX, 768] bf16
    const int* __restrict__ k1p, const int* __restrict__ k2p) {
  __shared__ unsigned short W[16 * 1024];  // 32 KB
  __shared__ float P[16 * 66];             // partial-sum combine
  const int l = threadIdx.x & 63, w = threadIdx.x >> 6;
  const int lr = l & 15, lk = l >> 4;
  const int bh = blockIdx.y, qt = blockIdx.x;
  const uint32_t kn1 = rfl(k1p[0]), kn2 = rfl(k2p[0]);  // 637, 575
  const size_t base = (size_t)bh * NY_ * 64;
  const unsigned short* Q = qbuf + base + (size_t)qt * 16 * 64;
  const unsigned short* Kp = kbuf + base;
  const unsigned short* Vt = vtbuf + base;

  // ---- Phase A: swapped QK^T. Wave w owns k-range [w*128, w*128+128). ----
  bf16x8 qf[2];
  #pragma unroll
  for (int s = 0; s < 2; s++)
    qf[s] = *(const bf16x8*)(Q + lr * 64 + s * 32 + lk * 8);

  #pragma unroll
  for (int kc = 0; kc < 2; kc++) {
    const int kbase = w * 128 + kc * 64;
    f32x4 acc[4];
    #pragma unroll
    for (int i = 0; i < 4; i++) acc[i] = (f32x4){0.f, 0.f, 0.f, 0.f};
    #pragma unroll
    for (int s = 0; s < 2; s++) {
      bf16x8 kf[4];
      #pragma unroll
      for (int i = 0; i < 4; i++)
        kf[i] = *(const bf16x8*)(Kp + (size_t)(kbase + i * 16 + lr) * 64 + s * 32 + lk * 8);
      #pragma unroll
      for (int i = 0; i < 4; i++)
        acc[i] = __builtin_amdgcn_mfma_f32_16x16x32_bf16(kf[i], qf[s], acc[i], 0, 0, 0);
    }
    #pragma unroll
    for (int i = 0; i < 4; i++) {
      const int kk = kbase + i * 16 + lk * 4;
      uint2 p;
      p.x = (uint32_t)f2bf(acc[i][0]) | ((uint32_t)f2bf(acc[i][1]) << 16);
      p.y = (uint32_t)f2bf(acc[i][2]) | ((uint32_t)f2bf(acc[i][3]) << 16);
      const int byte = lr * 2048 + ((kk * 2) ^ ((lr & 7) << 4));
      *(uint2*)((char*)W + byte) = p;
    }
  }
  __syncthreads();

  // ---- Phase B: dual k-th-largest + weights, float-space. Wave w: rows 2w, 2w+1. ----
  #pragma unroll 1
  for (int rr = 0; rr < 2; rr++) {
    char* rp = (char*)W + (2 * w + rr) * 2048;
    const uint4 u0 = *(uint4*)(rp + 16 * l);
    const uint4 u1 = *(uint4*)(rp + 16 * l + 1024);
    float s[16];
    {
      const uint32_t uu[8] = {u0.x, u0.y, u0.z, u0.w, u1.x, u1.y, u1.z, u1.w};
      #pragma unroll
      for (int i = 0; i < 8; i++) {
        s[2 * i]     = __uint_as_float(uu[i] << 16);
        s[2 * i + 1] = __uint_as_float(uu[i] & 0xFFFF0000u);
      }
    }
    // one pass: max, sum, sumsq (Gaussian seed for the searches)
    float mx = s[0], sm = 0.f, sq = 0.f;
    #pragma unroll
    for (int i = 0; i < 16; i++) {
      mx = fmaxf(mx, s[i]);
      sm += s[i];
      sq = fmaf(s[i], s[i], sq);
    }
    #pragma unroll
    for (int m = 32; m >= 1; m >>= 1) {
      mx = fmaxf(mx, __shfl_xor(mx, m));
      sm += __shfl_xor(sm, m);
      sq += __shfl_xor(sq, m);
    }
    const float mu = sm * (1.f / 1024.f);
    const float sg = sqrtf(fmaxf(sq * (1.f / 1024.f) - mu * mu, 0.f));
    // z ~= Phi^{-1}(1 - kn/1024) via linear approx around 0.5 (seed only)
    const float z1 = (0.5f - (float)kn1 * (1.f / 1024.f)) * 2.5066f;
    const float z2 = (0.5f - (float)kn2 * (1.f / 1024.f)) * 2.5066f;
    // elements below mx-130 have exp2(s-mx)==0 -> excluding them is exact
    const SRf r1 = searchf(s, kn1, mx - 130.f, 1024u, mx + 1.f, 0u, mu + z1 * sg);
    const SRf r2 = searchf(s, kn2, r1.t, r1.c, mx + 1.f, 0u, fmaxf(mu + z2 * sg, r1.t));
    const float t1 = r1.t, t2 = r2.t;

    // single exp pass; keep e[] for the weight pass
    float e[16], s1 = 0.f, s2 = 0.f;
    #pragma unroll
    for (int i = 0; i < 16; i++) {
      const float ev = exp2f(s[i] - mx);
      e[i] = ev;
      if (s[i] >= t1) s1 += ev;
      if (s[i] >= t2) s2 += ev;
    }
    const float et1 = exp2f(t1 - mx), et2 = exp2f(t2 - mx);  // e-space thresholds
    #pragma unroll
    for (int m = 32; m >= 1; m >>= 1) {
      s1 += __shfl_xor(s1, m);
      s2 += __shfl_xor(s2, m);
    }
    // clamps make c1/c2 finite unconditionally (no 0*inf pathway)
    const float c1 = 0.6f / fmaxf(s1, 1e-20f);
    const float c2v = 0.4f / fmaxf(s2, 1e-20f);
    const float c12 = c1 + c2v;
    uint32_t o[8];
    #pragma unroll
    for (int i = 0; i < 8; i++) {
      const float e0 = e[2 * i], e1 = e[2 * i + 1];
      const float w0 = e0 * ((e0 >= et1) ? ((e0 >= et2) ? c12 : c1) : 0.f);
      const float w1 = e1 * ((e1 >= et1) ? ((e1 >= et2) ? c12 : c1) : 0.f);
      o[i] = (uint32_t)f2bf(w0) | ((uint32_t)f2bf(w1) << 16);
    }
    *(uint4*)(rp + 16 * l)        = (uint4){o[0], o[1], o[2], o[3]};
    *(uint4*)(rp + 16 * l + 1024) = (uint4){o[4], o[5], o[6], o[7]};
  }
  __syncthreads();

  // ---- Phase C: PV, k-split across wave halves. d-block = (w&3)*16, k-half = w>>2. ----
  const int d0 = (w & 3) * 16;
  const int k0 = (w >> 2) * 512;
  f32x4 oacc = (f32x4){0.f, 0.f, 0.f, 0.f};
  #pragma unroll 4
  for (int kt2 = 0; kt2 < 512; kt2 += 32) {
    const int kt = k0 + kt2;
    const bf16x8 vf = *(const bf16x8*)(Vt + (size_t)(d0 + lr) * 1024 + kt + lk * 8);
    const int byte = lr * 2048 + (((kt + lk * 8) * 2) ^ ((lr & 7) << 4));
    const bf16x8 wf = *(const bf16x8*)((char*)W + byte);
    oacc = __builtin_amdgcn_mfma_f32_16x16x32_bf16(wf, vf, oacc, 0, 0, 0);
  }
  if (w >= 4) {
    #pragma unroll
    for (int g = 0; g < 4; g++)
      P[(lk * 4 + g) * 66 + d0 + lr] = oacc[g];
  }
  __syncthreads();
  if (w < 4) {
    const int b = bh / H_, h = bh % H_;
    #pragma unroll
    for (int g = 0; g < 4; g++) {
      const float v = oacc[g] + P[(lk * 4 + g) * 66 + d0 + lr];
      const int qrow = qt * 16 + lk * 4 + g;
      ao[(size_t)(b * NX_ + qrow) * C_ + h * 64 + d0 + lr] = f2bf(v);
    }
  }
}

// ---------------- launch ----------------
extern "C" void kernel_launch(void* const* d_in, const int* in_sizes, int n_in,
                              void* d_out, int out_size, void* d_ws, size_t ws_size,
                              hipStream_t stream) {
  const float* x   = (const float*)d_in[0];
  const float* y   = (const float*)d_in[1];
  const float* w1  = (const float*)d_in[2];
  const float* b1  = (const float*)d_in[3];
  const float* w2  = (const float*)d_in[4];
  const float* b2  = (const float*)d_in[5];
  const float* w3  = (const float*)d_in[6];
  const float* b3  = (const float*)d_in[7];
  const float* lnw = (const float*)d_in[8];
  const float* lnb = (const float*)d_in[9];
  const float* qw  = (const float*)d_in[10];
  const float* kvw = (const float*)d_in[11];
  const float* pw  = (const float*)d_in[12];
  const float* pb  = (const float*)d_in[13];
  const int* k1p   = (const int*)d_in[14];
  const int* k2p   = (const int*)d_in[15];

  char* ws = (char*)d_ws;
  size_t off = 0;
  auto alloc = [&](size_t bytes) {
    char* p = ws + off;
    off += (bytes + 255) & ~(size_t)255;
    return p;
  };
  const size_t NTOK = (size_t)B_ * NX_ * C_;
  unsigned short* x_bf   = (unsigned short*)alloc(NTOK * 2);
  unsigned short* ynorm  = (unsigned short*)alloc(NTOK * 2);
  unsigned short* qw_bf  = (unsigned short*)alloc((size_t)C_ * C_ * 2);
  unsigned short* kvw_bf = (unsigned short*)alloc((size_t)2 * C_ * C_ * 2);
  unsigned short* pw_bf  = (unsigned short*)alloc((size_t)C_ * C_ * 2);
  unsigned short* qbuf   = (unsigned short*)alloc(NTOK * 2);
  unsigned short* kbuf   = (unsigned short*)alloc(NTOK * 2);
  unsigned short* vtbuf  = (unsigned short*)alloc(NTOK * 2);
  unsigned short* aobuf  = (unsigned short*)alloc(NTOK * 2);

  pre_kernel<<<6400, 256, 0, stream>>>(
      y, w1, b1, w2, b2, w3, b3, lnw, lnb, ynorm,
      (const float4*)x, (uint2*)x_bf, (const float4*)qw, (uint2*)qw_bf,
      (const float4*)kvw, (uint2*)kvw_bf, (const float4*)pw, (uint2*)pw_bf);

  gemm_qkv_kernel<<<dim3(18, 32), 256, 0, stream>>>(
      x_bf, ynorm, qw_bf, kvw_bf, qbuf, kbuf, vtbuf);

  attn_kernel<<<dim3(NX_ / 16, B_ * H_), 512, 0, stream>>>(qbuf, kbuf, vtbuf, aobuf, k1p, k2p);

  gemm_proj_kernel<<<dim3(6, 32), 256, 0, stream>>>(
      aobuf, pw_bf, (float*)d_out, pb, x);
}